// Round 3
// baseline (150.379 us; speedup 1.0000x reference)
//
#include <hip/hip_runtime.h>
#include <math.h>

#define B 8
#define FCH 32
#define WI 256
#define HI 256
#define NW 32
#define NH 32
#define NBOX 1024
#define K 25
#define S 28
#define DZI 16
#define FEAT_FLAT (FCH*S*S)   /* 25088 */
#define FEAT4 (FEAT_FLAT/4)   /* 6272 */
#define OUT_FLAT (2*S*S)      /* 1568 */
#define SMIN 24.0f
#define SMAX 96.0f
#define BIG_SZ (K*B*WI*HI)    /* 13,107,200 */

#define NCHUNK 16
#define CH4 (FEAT4/NCHUNK)    /* 392 float4 groups per chunk */

/* output offsets (floats), in reference return order */
#define O_LOGIT_MU    0
#define O_LOGIT_FEW   8192
#define O_BIG_MASK    8392
#define O_BIG_MASK_NON (O_BIG_MASK + BIG_SZ)
#define O_BIG_IMG     (O_BIG_MASK_NON + BIG_SZ)
#define O_P_MAP       (O_BIG_IMG + BIG_SZ)
#define O_C_FEW       (O_P_MAP + 8192)
#define O_BX          (O_C_FEW + 200)
#define O_BY          (O_BX + 200)
#define O_BW          (O_BY + 200)
#define O_BH          (O_BW + 200)
#define O_Z_SAMPLE    (O_BH + 200)
#define O_KL_LOGIT    (O_Z_SAMPLE + 3200)
#define O_KL_ZWHERE   (O_KL_LOGIT + 8192)
#define O_KL_ZINST    (O_KL_ZWHERE + 800)

__device__ __forceinline__ float sigmoidf_(float x) { return 1.0f / (1.0f + expf(-x)); }
__device__ __forceinline__ float softplusf_(float x) { return fmaxf(x, 0.0f) + log1pf(expf(-fabsf(x))); }
/* fast variants (feed bulk outputs; abs err ~1e-6, threshold is >>) */
__device__ __forceinline__ float sig_fast(float x) { return 1.0f / (1.0f + __expf(-x)); }
__device__ __forceinline__ float sp_fast(float x)  { return fmaxf(x, 0.0f) + __logf(1.0f + __expf(-fabsf(x))); }
__device__ __forceinline__ float tanh_fast(float x) { /* x >= 0 */
    float e = __expf(-2.0f * x);
    return (1.0f - e) / (1.0f + e);
}

__device__ __forceinline__ float tap256(const float* img, int x, int y) {
    bool in = ((unsigned)x < 256u) && ((unsigned)y < 256u);
    int xc = min(max(x, 0), 255), yc = min(max(y, 0), 255);
    float v = img[xc * 256 + yc];
    return in ? v : 0.0f;
}

__device__ __forceinline__ float tap28(const float* img, int x, int y) {
    bool in = ((unsigned)x < 28u) && ((unsigned)y < 28u);
    int xc = min(max(x, 0), 27), yc = min(max(y, 0), 27);
    float v = img[xc * 28 + yc];
    return in ? v : 0.0f;
}

/* ------------- kernel T: misc maps + per-batch top-k + box params + kl_zwhere ------------- */
__global__ void topk_misc_kernel(const float* __restrict__ logit_mu,
                                 const float* __restrict__ zmu, const float* __restrict__ zstd,
                                 const float* __restrict__ w_zw, const float* __restrict__ b_zw,
                                 float* __restrict__ out, float* __restrict__ ws_boxes) {
    int b = blockIdx.x;
    int lane = threadIdx.x;          // 64 lanes, one wave
    const float* lg = logit_mu + b * NBOX;
    float vals[16];
    #pragma unroll
    for (int m = 0; m < 16; ++m) vals[m] = lg[m * 64 + lane];

    /* misc maps (fused: we already hold all 1024 logits) */
    #pragma unroll
    for (int m = 0; m < 16; ++m) {
        int idx = b * NBOX + m * 64 + lane;
        float x = vals[m];
        out[O_LOGIT_MU + idx] = x;
        float p = sigmoidf_(x);
        out[O_P_MAP + idx] = p;
        out[O_KL_LOGIT + idx] = 0.69314718055994531f + p * logf(p + 1e-8f) + (1.0f - p) * logf(1.0f - p + 1e-8f);
    }

    unsigned taken = 0;
    int sel_idx = 0;
    for (int ks = 0; ks < K; ++ks) {
        float bv = -INFINITY; int bi = 0x7fffffff;
        #pragma unroll
        for (int m = 0; m < 16; ++m) {
            if (!(taken & (1u << m))) {
                float v = vals[m]; int idx = m * 64 + lane;
                if (v > bv || (v == bv && idx < bi)) { bv = v; bi = idx; }
            }
        }
        #pragma unroll
        for (int sh = 32; sh >= 1; sh >>= 1) {
            float ov = __shfl_xor(bv, sh);
            int   oi = __shfl_xor(bi, sh);
            if (ov > bv || (ov == bv && oi < bi)) { bv = ov; bi = oi; }
        }
        if ((bi & 63) == lane) taken |= (1u << (bi >> 6));
        if (lane == ks) sel_idx = bi;
        if (lane == 0) {
            out[O_LOGIT_FEW + ks * B + b] = bv;
            out[O_C_FEW + ks * B + b] = sigmoidf_(bv);
        }
    }

    if (lane < K) {
        int idx = sel_idx;
        int w = idx >> 5, h = idx & 31;
        float mu_c[4];
        #pragma unroll
        for (int c = 0; c < 4; ++c) mu_c[c] = zmu[((b * 4 + c) * NW + w) * NH + h];
        float t[4];
        #pragma unroll
        for (int o = 0; o < 4; ++o) {
            float a = b_zw[o];
            #pragma unroll
            for (int c = 0; c < 4; ++c) a = fmaf(mu_c[c], w_zw[o * 4 + c], a);
            t[o] = sigmoidf_(a);
        }
        float bx = (float)WI * ((float)w + t[0]) / (float)NW;
        float by = (float)HI * ((float)h + t[1]) / (float)NH;
        float bw = SMIN + (SMAX - SMIN) * t[2];
        float bh = SMIN + (SMAX - SMIN) * t[3];
        int kb = lane * B + b;
        out[O_BX + kb] = bx;
        out[O_BY + kb] = by;
        out[O_BW + kb] = bw;
        out[O_BH + kb] = bh;
        ((float4*)ws_boxes)[kb] = make_float4(bx, by, bw, bh);
        #pragma unroll
        for (int c = 0; c < 4; ++c) {
            float m = mu_c[c];
            float sd = zstd[((b * 4 + c) * NW + w) * NH + h];
            out[O_KL_ZWHERE + kb * 4 + c] = 0.5f * (sd * sd + m * m - 1.0f) - logf(sd);
        }
    }
}

/* ------------- kernel C: crop + split-K encoder partials -------------
   grid = 25 box-groups x 16 K-chunks; block = 512 (8 waves, one wave = one box).
   All 8 waves stream the SAME weight chunk -> L1 amortization, 8x less L2 traffic. */
__global__ __launch_bounds__(512) void crop_enc_kernel(
        const float* __restrict__ features,
        const float* __restrict__ w_mu, const float* __restrict__ w_std,
        const float* __restrict__ ws_boxes, float* __restrict__ ws_part) {
    int blk = blockIdx.x;
    int g = blk >> 4, chunk = blk & 15;
    int wave = threadIdx.x >> 6, lane = threadIdx.x & 63;
    int kb = g * 8 + wave;          // box id (k*8+b flat)
    int b = kb & 7;
    float4 box = ((const float4*)ws_boxes)[kb];
    float x_lo = box.x - 0.5f * box.z, y_lo = box.y - 0.5f * box.w;
    float swx = box.z * (1.0f / 27.0f), swy = box.w * (1.0f / 27.0f);
    const float* fb = features + (size_t)b * (FCH * WI * HI);
    const float4* wm4 = (const float4*)w_mu;
    const float4* wsd4 = (const float4*)w_std;
    int base4 = chunk * CH4;

    float accm[DZI], accs[DZI];
    #pragma unroll
    for (int j = 0; j < DZI; ++j) { accm[j] = 0.0f; accs[j] = 0.0f; }

    for (int e = lane; e < CH4; e += 64) {
        int i4 = base4 + e;
        int i = i4 << 2;
        float v[4];
        #pragma unroll
        for (int q = 0; q < 4; ++q) {
            unsigned ii = (unsigned)(i + q);
            unsigned c = ii / 784u;
            unsigned s = ii - c * 784u;
            unsigned ix = s / 28u;
            unsigned iy = s - ix * 28u;
            float px = fmaf((float)ix, swx, x_lo);
            float py = fmaf((float)iy, swy, y_lo);
            const float* img = fb + (size_t)c * (WI * HI);
            float x0f = floorf(px), y0f = floorf(py);
            float fx = px - x0f, fy = py - y0f;
            int x0 = (int)x0f, y0 = (int)y0f;
            float a00 = tap256(img, x0, y0),     a01 = tap256(img, x0, y0 + 1);
            float a10 = tap256(img, x0 + 1, y0), a11 = tap256(img, x0 + 1, y0 + 1);
            v[q] = (1.0f - fx) * ((1.0f - fy) * a00 + fy * a01)
                 +         fx  * ((1.0f - fy) * a10 + fy * a11);
        }
        #pragma unroll
        for (int j = 0; j < DZI; ++j) {
            float4 w4 = wm4[j * FEAT4 + i4];
            accm[j] = fmaf(v[0], w4.x, fmaf(v[1], w4.y, fmaf(v[2], w4.z, fmaf(v[3], w4.w, accm[j]))));
            float4 s4 = wsd4[j * FEAT4 + i4];
            accs[j] = fmaf(v[0], s4.x, fmaf(v[1], s4.y, fmaf(v[2], s4.z, fmaf(v[3], s4.w, accs[j]))));
        }
    }

    #pragma unroll
    for (int j = 0; j < DZI; ++j) {
        #pragma unroll
        for (int sh = 32; sh >= 1; sh >>= 1) {
            accm[j] += __shfl_xor(accm[j], sh);
            accs[j] += __shfl_xor(accs[j], sh);
        }
    }
    if (lane == 0) {
        float4* p = (float4*)(ws_part + ((size_t)kb * NCHUNK + chunk) * 32);
        p[0] = make_float4(accm[0],  accm[1],  accm[2],  accm[3]);
        p[1] = make_float4(accm[4],  accm[5],  accm[6],  accm[7]);
        p[2] = make_float4(accm[8],  accm[9],  accm[10], accm[11]);
        p[3] = make_float4(accm[12], accm[13], accm[14], accm[15]);
        p[4] = make_float4(accs[0],  accs[1],  accs[2],  accs[3]);
        p[5] = make_float4(accs[4],  accs[5],  accs[6],  accs[7]);
        p[6] = make_float4(accs[8],  accs[9],  accs[10], accs[11]);
        p[7] = make_float4(accs[12], accs[13], accs[14], accs[15]);
    }
}

/* ------------- kernel D: finish encoder + decoder GEMV + activations ------------- */
__global__ __launch_bounds__(256) void dec_enc_kernel(
        const float* __restrict__ ws_part,
        const float* __restrict__ b_mu, const float* __restrict__ b_std,
        const float* __restrict__ w_dec, const float* __restrict__ b_dec,
        float* __restrict__ ws_small, float* __restrict__ out) {
    int kb = blockIdx.x;
    int t = threadIdx.x;
    __shared__ float zsh[DZI], spsh[DZI];
    if (t < 32) {
        float s = 0.0f;
        #pragma unroll
        for (int c = 0; c < NCHUNK; ++c) s += ws_part[((size_t)kb * NCHUNK + c) * 32 + t];
        if (t < DZI) zsh[t] = s + b_mu[t];
        else         spsh[t - DZI] = s + b_std[t - DZI];
    }
    __syncthreads();
    if (t < DZI) {
        float m = zsh[t];
        float sd = softplusf_(spsh[t]);
        out[O_Z_SAMPLE + kb * DZI + t] = m;
        out[O_KL_ZINST + kb * DZI + t] = 0.5f * (sd * sd + m * m - 1.0f) - logf(sd + 1e-8f);
    }
    float z[DZI];
    #pragma unroll
    for (int j = 0; j < DZI; ++j) z[j] = zsh[j];
    for (int o = t; o < OUT_FLAT; o += 256) {
        const float4* wd = (const float4*)(w_dec + o * DZI);
        float4 w0 = wd[0], w1 = wd[1], w2 = wd[2], w3 = wd[3];
        float a = b_dec[o];
        a = fmaf(z[0], w0.x, fmaf(z[1], w0.y, fmaf(z[2], w0.z, fmaf(z[3], w0.w, a))));
        a = fmaf(z[4], w1.x, fmaf(z[5], w1.y, fmaf(z[6], w1.z, fmaf(z[7], w1.w, a))));
        a = fmaf(z[8], w2.x, fmaf(z[9], w2.y, fmaf(z[10], w2.z, fmaf(z[11], w2.w, a))));
        a = fmaf(z[12], w3.x, fmaf(z[13], w3.y, fmaf(z[14], w3.z, fmaf(z[15], w3.w, a))));
        float r = (o < 784) ? sp_fast(a) : sig_fast(a);
        ws_small[(size_t)kb * OUT_FLAT + o] = r;
    }
}

/* ------------- kernel E: uncrop + mask compose, float4 stores -------------
   grid = B x 64 (4 u-rows per block); block 256: t>>6 -> du, (t&63)*4 -> v0 */
__device__ __forceinline__ void sample4_wi(const float* __restrict__ p0, float sx,
                                           float y_lo, float ih, int v0,
                                           float* __restrict__ w, float* __restrict__ im) {
    const float* p1 = p0 + 784;
    float x0f = floorf(sx); float fx = sx - x0f; int x0 = (int)x0f;
    #pragma unroll
    for (int q = 0; q < 4; ++q) {
        float sy = ((float)(v0 + q) - y_lo) * ih;
        float wv = 0.0f, iv = 0.0f;
        if (sy > -1.0f && sy < 28.0f) {
            float y0f = floorf(sy); float fy = sy - y0f; int y0 = (int)y0f;
            float a00 = tap28(p0, x0, y0),     a01 = tap28(p0, x0, y0 + 1);
            float a10 = tap28(p0, x0 + 1, y0), a11 = tap28(p0, x0 + 1, y0 + 1);
            wv = (1.0f - fx) * ((1.0f - fy) * a00 + fy * a01)
               +         fx  * ((1.0f - fy) * a10 + fy * a11);
            float c00 = tap28(p1, x0, y0),     c01 = tap28(p1, x0, y0 + 1);
            float c10 = tap28(p1, x0 + 1, y0), c11 = tap28(p1, x0 + 1, y0 + 1);
            iv = (1.0f - fx) * ((1.0f - fy) * c00 + fy * c01)
               +         fx  * ((1.0f - fy) * c10 + fy * c11);
        }
        w[q] = wv; im[q] = iv;
    }
}

__device__ __forceinline__ void sample4_w(const float* __restrict__ p0, float sx,
                                          float y_lo, float ih, int v0,
                                          float* __restrict__ w) {
    float x0f = floorf(sx); float fx = sx - x0f; int x0 = (int)x0f;
    #pragma unroll
    for (int q = 0; q < 4; ++q) {
        float sy = ((float)(v0 + q) - y_lo) * ih;
        float wv = 0.0f;
        if (sy > -1.0f && sy < 28.0f) {
            float y0f = floorf(sy); float fy = sy - y0f; int y0 = (int)y0f;
            float a00 = tap28(p0, x0, y0),     a01 = tap28(p0, x0, y0 + 1);
            float a10 = tap28(p0, x0 + 1, y0), a11 = tap28(p0, x0 + 1, y0 + 1);
            wv = (1.0f - fx) * ((1.0f - fy) * a00 + fy * a01)
               +         fx  * ((1.0f - fy) * a10 + fy * a11);
        }
        w[q] = wv;
    }
}

__global__ __launch_bounds__(256) void uncrop_kernel(const float* __restrict__ ws_small,
                                                     const float* __restrict__ ws_boxes,
                                                     float* __restrict__ out) {
    int blk = blockIdx.x;
    int b = blk >> 6;
    int u0 = (blk & 63) << 2;
    int t = threadIdx.x;
    int u = u0 + (t >> 6);
    int v0 = (t & 63) << 2;

    __shared__ float4 bt[K];   // (x_lo, y_lo, 27/cw, 27/ch)
    if (t < K) {
        float4 bx = ((const float4*)ws_boxes)[t * B + b];
        bt[t] = make_float4(bx.x - 0.5f * bx.z, bx.y - 0.5f * bx.w, 27.0f / bx.z, 27.0f / bx.w);
    }
    __syncthreads();

    float fu = (float)u;
    float sum[4] = {0.0f, 0.0f, 0.0f, 0.0f};
    #pragma unroll 1
    for (int k = 0; k < K; ++k) {
        float4 bb = bt[k];
        float sx = (fu - bb.x) * bb.z;
        float w[4] = {0, 0, 0, 0}, im[4] = {0, 0, 0, 0};
        if (sx > -1.0f && sx < 28.0f) {
            const float* p0 = ws_small + (size_t)(k * B + b) * OUT_FLAT;
            sample4_wi(p0, sx, bb.y, bb.w, v0, w, im);
        }
        #pragma unroll
        for (int q = 0; q < 4; ++q) sum[q] += w[q];
        size_t base = (((size_t)(k * B + b) * 256 + u) * 256 + v0);
        *(float4*)(out + O_BIG_IMG + base) = make_float4(im[0], im[1], im[2], im[3]);
        *(float4*)(out + O_BIG_MASK_NON + base) =
            make_float4(tanh_fast(w[0]), tanh_fast(w[1]), tanh_fast(w[2]), tanh_fast(w[3]));
    }
    float sc[4];
    #pragma unroll
    for (int q = 0; q < 4; ++q) sc[q] = tanh_fast(sum[q]) / fmaxf(sum[q], 1e-6f);
    #pragma unroll 1
    for (int k = 0; k < K; ++k) {
        float4 bb = bt[k];
        float sx = (fu - bb.x) * bb.z;
        float w[4] = {0, 0, 0, 0};
        if (sx > -1.0f && sx < 28.0f) {
            const float* p0 = ws_small + (size_t)(k * B + b) * OUT_FLAT;
            sample4_w(p0, sx, bb.y, bb.w, v0, w);
        }
        size_t base = (((size_t)(k * B + b) * 256 + u) * 256 + v0);
        *(float4*)(out + O_BIG_MASK + base) =
            make_float4(w[0] * sc[0], w[1] * sc[1], w[2] * sc[2], w[3] * sc[3]);
    }
}

extern "C" void kernel_launch(void* const* d_in, const int* in_sizes, int n_in,
                              void* d_out, int out_size, void* d_ws, size_t ws_size,
                              hipStream_t stream) {
    const float* features = (const float*)d_in[1];
    const float* zwhere_mu = (const float*)d_in[2];
    const float* zwhere_std = (const float*)d_in[3];
    const float* logit_mu = (const float*)d_in[4];
    const float* w_zwhere = (const float*)d_in[5];
    const float* b_zwhere = (const float*)d_in[6];
    const float* w_enc_mu = (const float*)d_in[7];
    const float* b_enc_mu = (const float*)d_in[8];
    const float* w_enc_std = (const float*)d_in[9];
    const float* b_enc_std = (const float*)d_in[10];
    const float* w_dec = (const float*)d_in[11];
    const float* b_dec = (const float*)d_in[12];
    float* out = (float*)d_out;

    float* ws_boxes = (float*)d_ws;                     // 800 floats
    float* ws_part  = ws_boxes + 200 * 4;               // 200*16*32 = 102400 floats
    float* ws_small = ws_part + 200 * NCHUNK * 32;      // 313600 floats

    hipLaunchKernelGGL(topk_misc_kernel, dim3(B), dim3(64), 0, stream,
                       logit_mu, zwhere_mu, zwhere_std, w_zwhere, b_zwhere, out, ws_boxes);
    hipLaunchKernelGGL(crop_enc_kernel, dim3(25 * NCHUNK), dim3(512), 0, stream,
                       features, w_enc_mu, w_enc_std, ws_boxes, ws_part);
    hipLaunchKernelGGL(dec_enc_kernel, dim3(K * B), dim3(256), 0, stream,
                       ws_part, b_enc_mu, b_enc_std, w_dec, b_dec, ws_small, out);
    hipLaunchKernelGGL(uncrop_kernel, dim3(B * 64), dim3(256), 0, stream,
                       ws_small, ws_boxes, out);
}

// Round 4
// 135.907 us; speedup vs baseline: 1.1065x; 1.1065x over previous
//
#include <hip/hip_runtime.h>
#include <math.h>

#define B 8
#define FCH 32
#define WI 256
#define HI 256
#define NW 32
#define NH 32
#define NBOX 1024
#define K 25
#define S 28
#define DZI 16
#define FEAT_FLAT (FCH*S*S)   /* 25088 */
#define FEAT4 (FEAT_FLAT/4)   /* 6272 */
#define OUT_FLAT (2*S*S)      /* 1568 */
#define SMIN 24.0f
#define SMAX 96.0f
#define BIG_SZ (K*B*WI*HI)    /* 13,107,200 */

#define NCHUNK 49
#define CH4 128               /* float4 groups per chunk; lane does 2 (lane, lane+64) */

/* output offsets (floats), in reference return order */
#define O_LOGIT_MU    0
#define O_LOGIT_FEW   8192
#define O_BIG_MASK    8392
#define O_BIG_MASK_NON (O_BIG_MASK + BIG_SZ)
#define O_BIG_IMG     (O_BIG_MASK_NON + BIG_SZ)
#define O_P_MAP       (O_BIG_IMG + BIG_SZ)
#define O_C_FEW       (O_P_MAP + 8192)
#define O_BX          (O_C_FEW + 200)
#define O_BY          (O_BX + 200)
#define O_BW          (O_BY + 200)
#define O_BH          (O_BW + 200)
#define O_Z_SAMPLE    (O_BH + 200)
#define O_KL_LOGIT    (O_Z_SAMPLE + 3200)
#define O_KL_ZWHERE   (O_KL_LOGIT + 8192)
#define O_KL_ZINST    (O_KL_ZWHERE + 800)

__device__ __forceinline__ float sigmoidf_(float x) { return 1.0f / (1.0f + expf(-x)); }
__device__ __forceinline__ float softplusf_(float x) { return fmaxf(x, 0.0f) + log1pf(expf(-fabsf(x))); }
__device__ __forceinline__ float sig_fast(float x) { return 1.0f / (1.0f + __expf(-x)); }
__device__ __forceinline__ float sp_fast(float x)  { return fmaxf(x, 0.0f) + __logf(1.0f + __expf(-fabsf(x))); }
__device__ __forceinline__ float tanh_fast(float x) { /* x >= 0 */
    float e = __expf(-2.0f * x);
    return (1.0f - e) / (1.0f + e);
}

__device__ __forceinline__ float tap256(const float* img, int x, int y) {
    bool in = ((unsigned)x < 256u) && ((unsigned)y < 256u);
    int xc = min(max(x, 0), 255), yc = min(max(y, 0), 255);
    float v = img[xc * 256 + yc];
    return in ? v : 0.0f;
}

__device__ __forceinline__ float tap28(const float* img, int x, int y) {
    bool in = ((unsigned)x < 28u) && ((unsigned)y < 28u);
    int xc = min(max(x, 0), 27), yc = min(max(y, 0), 27);
    float v = img[xc * 28 + yc];
    return in ? v : 0.0f;
}

/* ------------- kernel T: misc maps + per-batch top-k + box params + kl_zwhere ------------- */
__global__ void topk_misc_kernel(const float* __restrict__ logit_mu,
                                 const float* __restrict__ zmu, const float* __restrict__ zstd,
                                 const float* __restrict__ w_zw, const float* __restrict__ b_zw,
                                 float* __restrict__ out, float* __restrict__ ws_boxes) {
    int b = blockIdx.x;
    int lane = threadIdx.x;          // 64 lanes, one wave
    const float* lg = logit_mu + b * NBOX;
    float vals[16];
    #pragma unroll
    for (int m = 0; m < 16; ++m) vals[m] = lg[m * 64 + lane];

    #pragma unroll
    for (int m = 0; m < 16; ++m) {
        int idx = b * NBOX + m * 64 + lane;
        float x = vals[m];
        out[O_LOGIT_MU + idx] = x;
        float p = sigmoidf_(x);
        out[O_P_MAP + idx] = p;
        out[O_KL_LOGIT + idx] = 0.69314718055994531f + p * logf(p + 1e-8f) + (1.0f - p) * logf(1.0f - p + 1e-8f);
    }

    unsigned taken = 0;
    int sel_idx = 0;
    for (int ks = 0; ks < K; ++ks) {
        float bv = -INFINITY; int bi = 0x7fffffff;
        #pragma unroll
        for (int m = 0; m < 16; ++m) {
            if (!(taken & (1u << m))) {
                float v = vals[m]; int idx = m * 64 + lane;
                if (v > bv || (v == bv && idx < bi)) { bv = v; bi = idx; }
            }
        }
        #pragma unroll
        for (int sh = 32; sh >= 1; sh >>= 1) {
            float ov = __shfl_xor(bv, sh);
            int   oi = __shfl_xor(bi, sh);
            if (ov > bv || (ov == bv && oi < bi)) { bv = ov; bi = oi; }
        }
        if ((bi & 63) == lane) taken |= (1u << (bi >> 6));
        if (lane == ks) sel_idx = bi;
        if (lane == 0) {
            out[O_LOGIT_FEW + ks * B + b] = bv;
            out[O_C_FEW + ks * B + b] = sigmoidf_(bv);
        }
    }

    if (lane < K) {
        int idx = sel_idx;
        int w = idx >> 5, h = idx & 31;
        float mu_c[4];
        #pragma unroll
        for (int c = 0; c < 4; ++c) mu_c[c] = zmu[((b * 4 + c) * NW + w) * NH + h];
        float t[4];
        #pragma unroll
        for (int o = 0; o < 4; ++o) {
            float a = b_zw[o];
            #pragma unroll
            for (int c = 0; c < 4; ++c) a = fmaf(mu_c[c], w_zw[o * 4 + c], a);
            t[o] = sigmoidf_(a);
        }
        float bx = (float)WI * ((float)w + t[0]) / (float)NW;
        float by = (float)HI * ((float)h + t[1]) / (float)NH;
        float bw = SMIN + (SMAX - SMIN) * t[2];
        float bh = SMIN + (SMAX - SMIN) * t[3];
        int kb = lane * B + b;
        out[O_BX + kb] = bx;
        out[O_BY + kb] = by;
        out[O_BW + kb] = bw;
        out[O_BH + kb] = bh;
        ((float4*)ws_boxes)[kb] = make_float4(bx, by, bw, bh);
        #pragma unroll
        for (int c = 0; c < 4; ++c) {
            float m = mu_c[c];
            float sd = zstd[((b * 4 + c) * NW + w) * NH + h];
            out[O_KL_ZWHERE + kb * 4 + c] = 0.5f * (sd * sd + m * m - 1.0f) - logf(sd);
        }
    }
}

/* ------------- kernel C: crop + split-K encoder partials -------------
   grid = 25 box-groups x 49 K-chunks; block 512 (wave = box). Each lane owns exactly
   2 float4 groups (lane, lane+64) -> fully straight-line, staged weight loads. */
__device__ __forceinline__ float dot4(const float v[4], float4 w, float a) {
    return fmaf(v[0], w.x, fmaf(v[1], w.y, fmaf(v[2], w.z, fmaf(v[3], w.w, a))));
}

__device__ __forceinline__ void csample4(const float* __restrict__ fb, int i4,
                                         float x_lo, float y_lo, float swx, float swy,
                                         float v[4]) {
    int i = i4 << 2;
    unsigned c = (unsigned)i / 784u;
    unsigned s = (unsigned)i - c * 784u;
    unsigned ix = s / 28u;
    unsigned iy = s - ix * 28u;          /* iy multiple of 4; group stays in one row */
    const float* img = fb + (size_t)c * (WI * HI);
    float px = fmaf((float)ix, swx, x_lo);
    float x0f = floorf(px); float fx = px - x0f; int x0 = (int)x0f;
    #pragma unroll
    for (int q = 0; q < 4; ++q) {
        float py = fmaf((float)(iy + q), swy, y_lo);
        float y0f = floorf(py); float fy = py - y0f; int y0 = (int)y0f;
        float a00 = tap256(img, x0, y0),     a01 = tap256(img, x0, y0 + 1);
        float a10 = tap256(img, x0 + 1, y0), a11 = tap256(img, x0 + 1, y0 + 1);
        v[q] = (1.0f - fx) * ((1.0f - fy) * a00 + fy * a01)
             +         fx  * ((1.0f - fy) * a10 + fy * a11);
    }
}

__global__ __launch_bounds__(512) void crop_enc_kernel(
        const float* __restrict__ features,
        const float* __restrict__ w_mu, const float* __restrict__ w_std,
        const float* __restrict__ ws_boxes, float* __restrict__ ws_part) {
    int blk = blockIdx.x;
    int g = blk / NCHUNK, chunk = blk - g * NCHUNK;
    int wave = threadIdx.x >> 6, lane = threadIdx.x & 63;
    int kb = g * 8 + wave;          // box id (k*8+b flat)
    int b = kb & 7;
    float4 box = ((const float4*)ws_boxes)[kb];
    float x_lo = box.x - 0.5f * box.z, y_lo = box.y - 0.5f * box.w;
    float swx = box.z * (1.0f / 27.0f), swy = box.w * (1.0f / 27.0f);
    const float* fb = features + (size_t)b * (FCH * WI * HI);
    const float4* wm4 = (const float4*)w_mu;
    const float4* wsd4 = (const float4*)w_std;
    int i4a = chunk * CH4 + lane;
    int i4b = i4a + 64;

    /* both groups' samples first: 32 scattered taps in flight */
    float va[4], vb[4];
    csample4(fb, i4a, x_lo, y_lo, swx, swy, va);
    csample4(fb, i4b, x_lo, y_lo, swx, swy, vb);

    float accm[DZI], accs[DZI];
    #pragma unroll
    for (int j = 0; j < DZI; ++j) { accm[j] = 0.0f; accs[j] = 0.0f; }

    /* 4 batches of 8 rows; per batch: 16 staged float4 loads, then 64 FMAs */
    #pragma unroll
    for (int h = 0; h < 2; ++h) {
        float4 wa[8], wb[8];
        #pragma unroll
        for (int j = 0; j < 8; ++j) { wa[j] = wm4[(h * 8 + j) * FEAT4 + i4a]; wb[j] = wm4[(h * 8 + j) * FEAT4 + i4b]; }
        #pragma unroll
        for (int j = 0; j < 8; ++j) accm[h * 8 + j] = dot4(vb, wb[j], dot4(va, wa[j], accm[h * 8 + j]));
    }
    #pragma unroll
    for (int h = 0; h < 2; ++h) {
        float4 wa[8], wb[8];
        #pragma unroll
        for (int j = 0; j < 8; ++j) { wa[j] = wsd4[(h * 8 + j) * FEAT4 + i4a]; wb[j] = wsd4[(h * 8 + j) * FEAT4 + i4b]; }
        #pragma unroll
        for (int j = 0; j < 8; ++j) accs[h * 8 + j] = dot4(vb, wb[j], dot4(va, wa[j], accs[h * 8 + j]));
    }

    #pragma unroll
    for (int j = 0; j < DZI; ++j) {
        #pragma unroll
        for (int sh = 32; sh >= 1; sh >>= 1) {
            accm[j] += __shfl_xor(accm[j], sh);
            accs[j] += __shfl_xor(accs[j], sh);
        }
    }
    if (lane == 0) {
        float4* p = (float4*)(ws_part + ((size_t)kb * NCHUNK + chunk) * 32);
        p[0] = make_float4(accm[0],  accm[1],  accm[2],  accm[3]);
        p[1] = make_float4(accm[4],  accm[5],  accm[6],  accm[7]);
        p[2] = make_float4(accm[8],  accm[9],  accm[10], accm[11]);
        p[3] = make_float4(accm[12], accm[13], accm[14], accm[15]);
        p[4] = make_float4(accs[0],  accs[1],  accs[2],  accs[3]);
        p[5] = make_float4(accs[4],  accs[5],  accs[6],  accs[7]);
        p[6] = make_float4(accs[8],  accs[9],  accs[10], accs[11]);
        p[7] = make_float4(accs[12], accs[13], accs[14], accs[15]);
    }
}

/* ------------- kernel D: finish encoder + decoder GEMV + activations ------------- */
__global__ __launch_bounds__(256) void dec_enc_kernel(
        const float* __restrict__ ws_part,
        const float* __restrict__ b_mu, const float* __restrict__ b_std,
        const float* __restrict__ w_dec, const float* __restrict__ b_dec,
        float* __restrict__ ws_small, float* __restrict__ out) {
    int kb = blockIdx.x;
    int t = threadIdx.x;
    __shared__ float zsh[DZI], spsh[DZI];
    if (t < 32) {
        float s = 0.0f;
        for (int c = 0; c < NCHUNK; ++c) s += ws_part[((size_t)kb * NCHUNK + c) * 32 + t];
        if (t < DZI) zsh[t] = s + b_mu[t];
        else         spsh[t - DZI] = s + b_std[t - DZI];
    }
    __syncthreads();
    if (t < DZI) {
        float m = zsh[t];
        float sd = softplusf_(spsh[t]);
        out[O_Z_SAMPLE + kb * DZI + t] = m;
        out[O_KL_ZINST + kb * DZI + t] = 0.5f * (sd * sd + m * m - 1.0f) - logf(sd + 1e-8f);
    }
    float z[DZI];
    #pragma unroll
    for (int j = 0; j < DZI; ++j) z[j] = zsh[j];
    for (int o = t; o < OUT_FLAT; o += 256) {
        const float4* wd = (const float4*)(w_dec + o * DZI);
        float4 w0 = wd[0], w1 = wd[1], w2 = wd[2], w3 = wd[3];
        float a = b_dec[o];
        a = fmaf(z[0], w0.x, fmaf(z[1], w0.y, fmaf(z[2], w0.z, fmaf(z[3], w0.w, a))));
        a = fmaf(z[4], w1.x, fmaf(z[5], w1.y, fmaf(z[6], w1.z, fmaf(z[7], w1.w, a))));
        a = fmaf(z[8], w2.x, fmaf(z[9], w2.y, fmaf(z[10], w2.z, fmaf(z[11], w2.w, a))));
        a = fmaf(z[12], w3.x, fmaf(z[13], w3.y, fmaf(z[14], w3.z, fmaf(z[15], w3.w, a))));
        float r = (o < 784) ? sp_fast(a) : sig_fast(a);
        ws_small[(size_t)kb * OUT_FLAT + o] = r;
    }
}

/* ------------- kernel E: uncrop + mask compose, float4 stores ------------- */
__device__ __forceinline__ void sample4_wi(const float* __restrict__ p0, float sx,
                                           float y_lo, float ih, int v0,
                                           float* __restrict__ w, float* __restrict__ im) {
    const float* p1 = p0 + 784;
    float x0f = floorf(sx); float fx = sx - x0f; int x0 = (int)x0f;
    #pragma unroll
    for (int q = 0; q < 4; ++q) {
        float sy = ((float)(v0 + q) - y_lo) * ih;
        float wv = 0.0f, iv = 0.0f;
        if (sy > -1.0f && sy < 28.0f) {
            float y0f = floorf(sy); float fy = sy - y0f; int y0 = (int)y0f;
            float a00 = tap28(p0, x0, y0),     a01 = tap28(p0, x0, y0 + 1);
            float a10 = tap28(p0, x0 + 1, y0), a11 = tap28(p0, x0 + 1, y0 + 1);
            wv = (1.0f - fx) * ((1.0f - fy) * a00 + fy * a01)
               +         fx  * ((1.0f - fy) * a10 + fy * a11);
            float c00 = tap28(p1, x0, y0),     c01 = tap28(p1, x0, y0 + 1);
            float c10 = tap28(p1, x0 + 1, y0), c11 = tap28(p1, x0 + 1, y0 + 1);
            iv = (1.0f - fx) * ((1.0f - fy) * c00 + fy * c01)
               +         fx  * ((1.0f - fy) * c10 + fy * c11);
        }
        w[q] = wv; im[q] = iv;
    }
}

__device__ __forceinline__ void sample4_w(const float* __restrict__ p0, float sx,
                                          float y_lo, float ih, int v0,
                                          float* __restrict__ w) {
    float x0f = floorf(sx); float fx = sx - x0f; int x0 = (int)x0f;
    #pragma unroll
    for (int q = 0; q < 4; ++q) {
        float sy = ((float)(v0 + q) - y_lo) * ih;
        float wv = 0.0f;
        if (sy > -1.0f && sy < 28.0f) {
            float y0f = floorf(sy); float fy = sy - y0f; int y0 = (int)y0f;
            float a00 = tap28(p0, x0, y0),     a01 = tap28(p0, x0, y0 + 1);
            float a10 = tap28(p0, x0 + 1, y0), a11 = tap28(p0, x0 + 1, y0 + 1);
            wv = (1.0f - fx) * ((1.0f - fy) * a00 + fy * a01)
               +         fx  * ((1.0f - fy) * a10 + fy * a11);
        }
        w[q] = wv;
    }
}

__global__ __launch_bounds__(256) void uncrop_kernel(const float* __restrict__ ws_small,
                                                     const float* __restrict__ ws_boxes,
                                                     float* __restrict__ out) {
    int blk = blockIdx.x;
    int b = blk >> 6;
    int u0 = (blk & 63) << 2;
    int t = threadIdx.x;
    int u = u0 + (t >> 6);
    int v0 = (t & 63) << 2;

    __shared__ float4 bt[K];   // (x_lo, y_lo, 27/cw, 27/ch)
    if (t < K) {
        float4 bx = ((const float4*)ws_boxes)[t * B + b];
        bt[t] = make_float4(bx.x - 0.5f * bx.z, bx.y - 0.5f * bx.w, 27.0f / bx.z, 27.0f / bx.w);
    }
    __syncthreads();

    float fu = (float)u;
    float sum[4] = {0.0f, 0.0f, 0.0f, 0.0f};
    #pragma unroll 1
    for (int k = 0; k < K; ++k) {
        float4 bb = bt[k];
        float sx = (fu - bb.x) * bb.z;
        float w[4] = {0, 0, 0, 0}, im[4] = {0, 0, 0, 0};
        if (sx > -1.0f && sx < 28.0f) {
            const float* p0 = ws_small + (size_t)(k * B + b) * OUT_FLAT;
            sample4_wi(p0, sx, bb.y, bb.w, v0, w, im);
        }
        #pragma unroll
        for (int q = 0; q < 4; ++q) sum[q] += w[q];
        size_t base = (((size_t)(k * B + b) * 256 + u) * 256 + v0);
        *(float4*)(out + O_BIG_IMG + base) = make_float4(im[0], im[1], im[2], im[3]);
        *(float4*)(out + O_BIG_MASK_NON + base) =
            make_float4(tanh_fast(w[0]), tanh_fast(w[1]), tanh_fast(w[2]), tanh_fast(w[3]));
    }
    float sc[4];
    #pragma unroll
    for (int q = 0; q < 4; ++q) sc[q] = tanh_fast(sum[q]) / fmaxf(sum[q], 1e-6f);
    #pragma unroll 1
    for (int k = 0; k < K; ++k) {
        float4 bb = bt[k];
        float sx = (fu - bb.x) * bb.z;
        float w[4] = {0, 0, 0, 0};
        if (sx > -1.0f && sx < 28.0f) {
            const float* p0 = ws_small + (size_t)(k * B + b) * OUT_FLAT;
            sample4_w(p0, sx, bb.y, bb.w, v0, w);
        }
        size_t base = (((size_t)(k * B + b) * 256 + u) * 256 + v0);
        *(float4*)(out + O_BIG_MASK + base) =
            make_float4(w[0] * sc[0], w[1] * sc[1], w[2] * sc[2], w[3] * sc[3]);
    }
}

extern "C" void kernel_launch(void* const* d_in, const int* in_sizes, int n_in,
                              void* d_out, int out_size, void* d_ws, size_t ws_size,
                              hipStream_t stream) {
    const float* features = (const float*)d_in[1];
    const float* zwhere_mu = (const float*)d_in[2];
    const float* zwhere_std = (const float*)d_in[3];
    const float* logit_mu = (const float*)d_in[4];
    const float* w_zwhere = (const float*)d_in[5];
    const float* b_zwhere = (const float*)d_in[6];
    const float* w_enc_mu = (const float*)d_in[7];
    const float* b_enc_mu = (const float*)d_in[8];
    const float* w_enc_std = (const float*)d_in[9];
    const float* b_enc_std = (const float*)d_in[10];
    const float* w_dec = (const float*)d_in[11];
    const float* b_dec = (const float*)d_in[12];
    float* out = (float*)d_out;

    float* ws_boxes = (float*)d_ws;                     // 800 floats
    float* ws_part  = ws_boxes + 200 * 4;               // 200*49*32 = 313600 floats
    float* ws_small = ws_part + 200 * NCHUNK * 32;      // 313600 floats

    hipLaunchKernelGGL(topk_misc_kernel, dim3(B), dim3(64), 0, stream,
                       logit_mu, zwhere_mu, zwhere_std, w_zwhere, b_zwhere, out, ws_boxes);
    hipLaunchKernelGGL(crop_enc_kernel, dim3(25 * NCHUNK), dim3(512), 0, stream,
                       features, w_enc_mu, w_enc_std, ws_boxes, ws_part);
    hipLaunchKernelGGL(dec_enc_kernel, dim3(K * B), dim3(256), 0, stream,
                       ws_part, b_enc_mu, b_enc_std, w_dec, b_dec, ws_small, out);
    hipLaunchKernelGGL(uncrop_kernel, dim3(B * 64), dim3(256), 0, stream,
                       ws_small, ws_boxes, out);
}

// Round 5
// 134.084 us; speedup vs baseline: 1.1215x; 1.0136x over previous
//
#include <hip/hip_runtime.h>
#include <math.h>

#define B 8
#define FCH 32
#define WI 256
#define HI 256
#define NW 32
#define NH 32
#define NBOX 1024
#define K 25
#define S 28
#define DZI 16
#define FEAT_FLAT (FCH*S*S)   /* 25088 */
#define FEAT4 (FEAT_FLAT/4)   /* 6272 */
#define OUT_FLAT (2*S*S)      /* 1568 */
#define SMIN 24.0f
#define SMAX 96.0f
#define BIG_SZ (K*B*WI*HI)    /* 13,107,200 */

#define NCHUNK 49
#define CH4 128               /* float4 groups per chunk; lane does 2 (lane, lane+64) */

/* output offsets (floats), in reference return order */
#define O_LOGIT_MU    0
#define O_LOGIT_FEW   8192
#define O_BIG_MASK    8392
#define O_BIG_MASK_NON (O_BIG_MASK + BIG_SZ)
#define O_BIG_IMG     (O_BIG_MASK_NON + BIG_SZ)
#define O_P_MAP       (O_BIG_IMG + BIG_SZ)
#define O_C_FEW       (O_P_MAP + 8192)
#define O_BX          (O_C_FEW + 200)
#define O_BY          (O_BX + 200)
#define O_BW          (O_BY + 200)
#define O_BH          (O_BW + 200)
#define O_Z_SAMPLE    (O_BH + 200)
#define O_KL_LOGIT    (O_Z_SAMPLE + 3200)
#define O_KL_ZWHERE   (O_KL_LOGIT + 8192)
#define O_KL_ZINST    (O_KL_ZWHERE + 800)

__device__ __forceinline__ float sigmoidf_(float x) { return 1.0f / (1.0f + expf(-x)); }
__device__ __forceinline__ float softplusf_(float x) { return fmaxf(x, 0.0f) + log1pf(expf(-fabsf(x))); }
__device__ __forceinline__ float sig_fast(float x) { return 1.0f / (1.0f + __expf(-x)); }
__device__ __forceinline__ float sp_fast(float x)  { return fmaxf(x, 0.0f) + __logf(1.0f + __expf(-fabsf(x))); }
__device__ __forceinline__ float tanh_fast(float x) { /* x >= 0 */
    float e = __expf(-2.0f * x);
    return (1.0f - e) / (1.0f + e);
}

__device__ __forceinline__ float tap256(const float* img, int x, int y) {
    bool in = ((unsigned)x < 256u) && ((unsigned)y < 256u);
    int xc = min(max(x, 0), 255), yc = min(max(y, 0), 255);
    float v = img[xc * 256 + yc];
    return in ? v : 0.0f;
}

__device__ __forceinline__ float tap28(const float* img, int x, int y) {
    bool in = ((unsigned)x < 28u) && ((unsigned)y < 28u);
    int xc = min(max(x, 0), 27), yc = min(max(y, 0), 27);
    float v = img[xc * 28 + yc];
    return in ? v : 0.0f;
}

/* ------------- kernel T: misc maps + per-batch top-k + box params + kl_zwhere ------------- */
__global__ void topk_misc_kernel(const float* __restrict__ logit_mu,
                                 const float* __restrict__ zmu, const float* __restrict__ zstd,
                                 const float* __restrict__ w_zw, const float* __restrict__ b_zw,
                                 float* __restrict__ out, float* __restrict__ ws_boxes) {
    int b = blockIdx.x;
    int lane = threadIdx.x;          // 64 lanes, one wave
    const float* lg = logit_mu + b * NBOX;
    float vals[16];
    #pragma unroll
    for (int m = 0; m < 16; ++m) vals[m] = lg[m * 64 + lane];

    #pragma unroll
    for (int m = 0; m < 16; ++m) {
        int idx = b * NBOX + m * 64 + lane;
        float x = vals[m];
        out[O_LOGIT_MU + idx] = x;
        float p = sigmoidf_(x);
        out[O_P_MAP + idx] = p;
        out[O_KL_LOGIT + idx] = 0.69314718055994531f + p * logf(p + 1e-8f) + (1.0f - p) * logf(1.0f - p + 1e-8f);
    }

    unsigned taken = 0;
    int sel_idx = 0;
    for (int ks = 0; ks < K; ++ks) {
        float bv = -INFINITY; int bi = 0x7fffffff;
        #pragma unroll
        for (int m = 0; m < 16; ++m) {
            if (!(taken & (1u << m))) {
                float v = vals[m]; int idx = m * 64 + lane;
                if (v > bv || (v == bv && idx < bi)) { bv = v; bi = idx; }
            }
        }
        #pragma unroll
        for (int sh = 32; sh >= 1; sh >>= 1) {
            float ov = __shfl_xor(bv, sh);
            int   oi = __shfl_xor(bi, sh);
            if (ov > bv || (ov == bv && oi < bi)) { bv = ov; bi = oi; }
        }
        if ((bi & 63) == lane) taken |= (1u << (bi >> 6));
        if (lane == ks) sel_idx = bi;
        if (lane == 0) {
            out[O_LOGIT_FEW + ks * B + b] = bv;
            out[O_C_FEW + ks * B + b] = sigmoidf_(bv);
        }
    }

    if (lane < K) {
        int idx = sel_idx;
        int w = idx >> 5, h = idx & 31;
        float mu_c[4];
        #pragma unroll
        for (int c = 0; c < 4; ++c) mu_c[c] = zmu[((b * 4 + c) * NW + w) * NH + h];
        float t[4];
        #pragma unroll
        for (int o = 0; o < 4; ++o) {
            float a = b_zw[o];
            #pragma unroll
            for (int c = 0; c < 4; ++c) a = fmaf(mu_c[c], w_zw[o * 4 + c], a);
            t[o] = sigmoidf_(a);
        }
        float bx = (float)WI * ((float)w + t[0]) / (float)NW;
        float by = (float)HI * ((float)h + t[1]) / (float)NH;
        float bw = SMIN + (SMAX - SMIN) * t[2];
        float bh = SMIN + (SMAX - SMIN) * t[3];
        int kb = lane * B + b;
        out[O_BX + kb] = bx;
        out[O_BY + kb] = by;
        out[O_BW + kb] = bw;
        out[O_BH + kb] = bh;
        ((float4*)ws_boxes)[kb] = make_float4(bx, by, bw, bh);
        #pragma unroll
        for (int c = 0; c < 4; ++c) {
            float m = mu_c[c];
            float sd = zstd[((b * 4 + c) * NW + w) * NH + h];
            out[O_KL_ZWHERE + kb * 4 + c] = 0.5f * (sd * sd + m * m - 1.0f) - logf(sd);
        }
    }
}

/* ------------- kernel W: materialize crops (pure gather, massive TLP) -------------
   grid = (49, 200), 128 threads; thread -> one float4 group of one box. */
__device__ __forceinline__ void csample4(const float* __restrict__ fb, int i4,
                                         float x_lo, float y_lo, float swx, float swy,
                                         float v[4]) {
    int i = i4 << 2;
    unsigned c = (unsigned)i / 784u;
    unsigned s = (unsigned)i - c * 784u;
    unsigned ix = s / 28u;
    unsigned iy = s - ix * 28u;          /* iy multiple of 4; group stays in one row */
    const float* img = fb + (size_t)c * (WI * HI);
    float px = fmaf((float)ix, swx, x_lo);
    float x0f = floorf(px); float fx = px - x0f; int x0 = (int)x0f;
    #pragma unroll
    for (int q = 0; q < 4; ++q) {
        float py = fmaf((float)(iy + q), swy, y_lo);
        float y0f = floorf(py); float fy = py - y0f; int y0 = (int)y0f;
        float a00 = tap256(img, x0, y0),     a01 = tap256(img, x0, y0 + 1);
        float a10 = tap256(img, x0 + 1, y0), a11 = tap256(img, x0 + 1, y0 + 1);
        v[q] = (1.0f - fx) * ((1.0f - fy) * a00 + fy * a01)
             +         fx  * ((1.0f - fy) * a10 + fy * a11);
    }
}

__global__ __launch_bounds__(128) void crop_writer_kernel(
        const float* __restrict__ features, const float* __restrict__ ws_boxes,
        float* __restrict__ crop) {
    int kb = blockIdx.y;
    int i4 = blockIdx.x * 128 + threadIdx.x;
    int b = kb & 7;
    float4 box = ((const float4*)ws_boxes)[kb];
    float x_lo = box.x - 0.5f * box.z, y_lo = box.y - 0.5f * box.w;
    float swx = box.z * (1.0f / 27.0f), swy = box.w * (1.0f / 27.0f);
    const float* fb = features + (size_t)b * (FCH * WI * HI);
    float v[4];
    csample4(fb, i4, x_lo, y_lo, swx, swy, v);
    ((float4*)crop)[(size_t)kb * FEAT4 + i4] = make_float4(v[0], v[1], v[2], v[3]);
}

/* ------------- kernel G: split-K encoder GEMM over materialized crops -------------
   grid = 25 box-groups x 49 K-chunks; block 512 (wave = box). Lane owns 2 float4
   crop groups (contiguous loads) x 32 weight rows. Pairing-tree reduction. */
__device__ __forceinline__ float dot4f(float4 v, float4 w, float a) {
    return fmaf(v.x, w.x, fmaf(v.y, w.y, fmaf(v.z, w.z, fmaf(v.w, w.w, a))));
}

__global__ __launch_bounds__(512) void enc_gemm_kernel(
        const float* __restrict__ crop,
        const float* __restrict__ w_mu, const float* __restrict__ w_std,
        float* __restrict__ ws_part) {
    int blk = blockIdx.x;
    int g = blk / NCHUNK, chunk = blk - g * NCHUNK;
    int wave = threadIdx.x >> 6, lane = threadIdx.x & 63;
    int kb = g * 8 + wave;          // box id (k*8+b flat)
    const float4* wm4 = (const float4*)w_mu;
    const float4* wsd4 = (const float4*)w_std;
    const float4* cp4 = (const float4*)crop + (size_t)kb * FEAT4;
    int i4a = chunk * CH4 + lane;
    int i4b = i4a + 64;

    float4 va = cp4[i4a];
    float4 vb = cp4[i4b];

    float cur[32];                  /* 0..15 mu accs, 16..31 std accs */
    #pragma unroll
    for (int j = 0; j < 32; ++j) cur[j] = 0.0f;

    #pragma unroll
    for (int h = 0; h < 2; ++h) {
        float4 wa[8], wb[8];
        #pragma unroll
        for (int j = 0; j < 8; ++j) { wa[j] = wm4[(h * 8 + j) * FEAT4 + i4a]; wb[j] = wm4[(h * 8 + j) * FEAT4 + i4b]; }
        #pragma unroll
        for (int j = 0; j < 8; ++j) cur[h * 8 + j] = dot4f(vb, wb[j], dot4f(va, wa[j], cur[h * 8 + j]));
    }
    #pragma unroll
    for (int h = 0; h < 2; ++h) {
        float4 wa[8], wb[8];
        #pragma unroll
        for (int j = 0; j < 8; ++j) { wa[j] = wsd4[(h * 8 + j) * FEAT4 + i4a]; wb[j] = wsd4[(h * 8 + j) * FEAT4 + i4b]; }
        #pragma unroll
        for (int j = 0; j < 8; ++j) cur[16 + h * 8 + j] = dot4f(vb, wb[j], dot4f(va, wa[j], cur[16 + h * 8 + j]));
    }

    /* pairing-tree reduce: 32 values/lane -> lane l<32 holds full 64-lane sum of acc l */
    {   bool bit = (lane & 1) != 0; float nx[16];
        #pragma unroll
        for (int j = 0; j < 16; ++j) {
            float keep = bit ? cur[2*j+1] : cur[2*j];
            float send = bit ? cur[2*j]   : cur[2*j+1];
            nx[j] = keep + __shfl_xor(send, 1);
        }
        #pragma unroll
        for (int j = 0; j < 16; ++j) cur[j] = nx[j];
    }
    {   bool bit = (lane & 2) != 0; float nx[8];
        #pragma unroll
        for (int j = 0; j < 8; ++j) {
            float keep = bit ? cur[2*j+1] : cur[2*j];
            float send = bit ? cur[2*j]   : cur[2*j+1];
            nx[j] = keep + __shfl_xor(send, 2);
        }
        #pragma unroll
        for (int j = 0; j < 8; ++j) cur[j] = nx[j];
    }
    {   bool bit = (lane & 4) != 0; float nx[4];
        #pragma unroll
        for (int j = 0; j < 4; ++j) {
            float keep = bit ? cur[2*j+1] : cur[2*j];
            float send = bit ? cur[2*j]   : cur[2*j+1];
            nx[j] = keep + __shfl_xor(send, 4);
        }
        #pragma unroll
        for (int j = 0; j < 4; ++j) cur[j] = nx[j];
    }
    {   bool bit = (lane & 8) != 0; float nx[2];
        #pragma unroll
        for (int j = 0; j < 2; ++j) {
            float keep = bit ? cur[2*j+1] : cur[2*j];
            float send = bit ? cur[2*j]   : cur[2*j+1];
            nx[j] = keep + __shfl_xor(send, 8);
        }
        cur[0] = nx[0]; cur[1] = nx[1];
    }
    {   bool bit = (lane & 16) != 0;
        float keep = bit ? cur[1] : cur[0];
        float send = bit ? cur[0] : cur[1];
        cur[0] = keep + __shfl_xor(send, 16);
    }
    float tot = cur[0] + __shfl_xor(cur[0], 32);
    if (lane < 32) ws_part[((size_t)kb * NCHUNK + chunk) * 32 + lane] = tot;
}

/* ------------- kernel D: finish encoder + decoder GEMV + activations ------------- */
__global__ __launch_bounds__(256) void dec_enc_kernel(
        const float* __restrict__ ws_part,
        const float* __restrict__ b_mu, const float* __restrict__ b_std,
        const float* __restrict__ w_dec, const float* __restrict__ b_dec,
        float* __restrict__ ws_small, float* __restrict__ out) {
    int kb = blockIdx.x;
    int t = threadIdx.x;
    __shared__ float zsh[DZI], spsh[DZI];
    if (t < 32) {
        float s = 0.0f;
        for (int c = 0; c < NCHUNK; ++c) s += ws_part[((size_t)kb * NCHUNK + c) * 32 + t];
        if (t < DZI) zsh[t] = s + b_mu[t];
        else         spsh[t - DZI] = s + b_std[t - DZI];
    }
    __syncthreads();
    if (t < DZI) {
        float m = zsh[t];
        float sd = softplusf_(spsh[t]);
        out[O_Z_SAMPLE + kb * DZI + t] = m;
        out[O_KL_ZINST + kb * DZI + t] = 0.5f * (sd * sd + m * m - 1.0f) - logf(sd + 1e-8f);
    }
    float z[DZI];
    #pragma unroll
    for (int j = 0; j < DZI; ++j) z[j] = zsh[j];
    for (int o = t; o < OUT_FLAT; o += 256) {
        const float4* wd = (const float4*)(w_dec + o * DZI);
        float4 w0 = wd[0], w1 = wd[1], w2 = wd[2], w3 = wd[3];
        float a = b_dec[o];
        a = fmaf(z[0], w0.x, fmaf(z[1], w0.y, fmaf(z[2], w0.z, fmaf(z[3], w0.w, a))));
        a = fmaf(z[4], w1.x, fmaf(z[5], w1.y, fmaf(z[6], w1.z, fmaf(z[7], w1.w, a))));
        a = fmaf(z[8], w2.x, fmaf(z[9], w2.y, fmaf(z[10], w2.z, fmaf(z[11], w2.w, a))));
        a = fmaf(z[12], w3.x, fmaf(z[13], w3.y, fmaf(z[14], w3.z, fmaf(z[15], w3.w, a))));
        float r = (o < 784) ? sp_fast(a) : sig_fast(a);
        ws_small[(size_t)kb * OUT_FLAT + o] = r;
    }
}

/* ------------- kernel E: uncrop + mask compose, float4 stores ------------- */
__device__ __forceinline__ void sample4_wi(const float* __restrict__ p0, float sx,
                                           float y_lo, float ih, int v0,
                                           float* __restrict__ w, float* __restrict__ im) {
    const float* p1 = p0 + 784;
    float x0f = floorf(sx); float fx = sx - x0f; int x0 = (int)x0f;
    #pragma unroll
    for (int q = 0; q < 4; ++q) {
        float sy = ((float)(v0 + q) - y_lo) * ih;
        float wv = 0.0f, iv = 0.0f;
        if (sy > -1.0f && sy < 28.0f) {
            float y0f = floorf(sy); float fy = sy - y0f; int y0 = (int)y0f;
            float a00 = tap28(p0, x0, y0),     a01 = tap28(p0, x0, y0 + 1);
            float a10 = tap28(p0, x0 + 1, y0), a11 = tap28(p0, x0 + 1, y0 + 1);
            wv = (1.0f - fx) * ((1.0f - fy) * a00 + fy * a01)
               +         fx  * ((1.0f - fy) * a10 + fy * a11);
            float c00 = tap28(p1, x0, y0),     c01 = tap28(p1, x0, y0 + 1);
            float c10 = tap28(p1, x0 + 1, y0), c11 = tap28(p1, x0 + 1, y0 + 1);
            iv = (1.0f - fx) * ((1.0f - fy) * c00 + fy * c01)
               +         fx  * ((1.0f - fy) * c10 + fy * c11);
        }
        w[q] = wv; im[q] = iv;
    }
}

__device__ __forceinline__ void sample4_w(const float* __restrict__ p0, float sx,
                                          float y_lo, float ih, int v0,
                                          float* __restrict__ w) {
    float x0f = floorf(sx); float fx = sx - x0f; int x0 = (int)x0f;
    #pragma unroll
    for (int q = 0; q < 4; ++q) {
        float sy = ((float)(v0 + q) - y_lo) * ih;
        float wv = 0.0f;
        if (sy > -1.0f && sy < 28.0f) {
            float y0f = floorf(sy); float fy = sy - y0f; int y0 = (int)y0f;
            float a00 = tap28(p0, x0, y0),     a01 = tap28(p0, x0, y0 + 1);
            float a10 = tap28(p0, x0 + 1, y0), a11 = tap28(p0, x0 + 1, y0 + 1);
            wv = (1.0f - fx) * ((1.0f - fy) * a00 + fy * a01)
               +         fx  * ((1.0f - fy) * a10 + fy * a11);
        }
        w[q] = wv;
    }
}

__global__ __launch_bounds__(256) void uncrop_kernel(const float* __restrict__ ws_small,
                                                     const float* __restrict__ ws_boxes,
                                                     float* __restrict__ out) {
    int blk = blockIdx.x;
    int b = blk >> 6;
    int u0 = (blk & 63) << 2;
    int t = threadIdx.x;
    int u = u0 + (t >> 6);
    int v0 = (t & 63) << 2;

    __shared__ float4 bt[K];   // (x_lo, y_lo, 27/cw, 27/ch)
    if (t < K) {
        float4 bx = ((const float4*)ws_boxes)[t * B + b];
        bt[t] = make_float4(bx.x - 0.5f * bx.z, bx.y - 0.5f * bx.w, 27.0f / bx.z, 27.0f / bx.w);
    }
    __syncthreads();

    float fu = (float)u;
    float sum[4] = {0.0f, 0.0f, 0.0f, 0.0f};
    #pragma unroll 1
    for (int k = 0; k < K; ++k) {
        float4 bb = bt[k];
        float sx = (fu - bb.x) * bb.z;
        float w[4] = {0, 0, 0, 0}, im[4] = {0, 0, 0, 0};
        if (sx > -1.0f && sx < 28.0f) {
            const float* p0 = ws_small + (size_t)(k * B + b) * OUT_FLAT;
            sample4_wi(p0, sx, bb.y, bb.w, v0, w, im);
        }
        #pragma unroll
        for (int q = 0; q < 4; ++q) sum[q] += w[q];
        size_t base = (((size_t)(k * B + b) * 256 + u) * 256 + v0);
        *(float4*)(out + O_BIG_IMG + base) = make_float4(im[0], im[1], im[2], im[3]);
        *(float4*)(out + O_BIG_MASK_NON + base) =
            make_float4(tanh_fast(w[0]), tanh_fast(w[1]), tanh_fast(w[2]), tanh_fast(w[3]));
    }
    float sc[4];
    #pragma unroll
    for (int q = 0; q < 4; ++q) sc[q] = tanh_fast(sum[q]) / fmaxf(sum[q], 1e-6f);
    #pragma unroll 1
    for (int k = 0; k < K; ++k) {
        float4 bb = bt[k];
        float sx = (fu - bb.x) * bb.z;
        float w[4] = {0, 0, 0, 0};
        if (sx > -1.0f && sx < 28.0f) {
            const float* p0 = ws_small + (size_t)(k * B + b) * OUT_FLAT;
            sample4_w(p0, sx, bb.y, bb.w, v0, w);
        }
        size_t base = (((size_t)(k * B + b) * 256 + u) * 256 + v0);
        *(float4*)(out + O_BIG_MASK + base) =
            make_float4(w[0] * sc[0], w[1] * sc[1], w[2] * sc[2], w[3] * sc[3]);
    }
}

extern "C" void kernel_launch(void* const* d_in, const int* in_sizes, int n_in,
                              void* d_out, int out_size, void* d_ws, size_t ws_size,
                              hipStream_t stream) {
    const float* features = (const float*)d_in[1];
    const float* zwhere_mu = (const float*)d_in[2];
    const float* zwhere_std = (const float*)d_in[3];
    const float* logit_mu = (const float*)d_in[4];
    const float* w_zwhere = (const float*)d_in[5];
    const float* b_zwhere = (const float*)d_in[6];
    const float* w_enc_mu = (const float*)d_in[7];
    const float* b_enc_mu = (const float*)d_in[8];
    const float* w_enc_std = (const float*)d_in[9];
    const float* b_enc_std = (const float*)d_in[10];
    const float* w_dec = (const float*)d_in[11];
    const float* b_dec = (const float*)d_in[12];
    float* out = (float*)d_out;

    float* ws_boxes = (float*)d_ws;                     // 800 floats
    float* ws_part  = ws_boxes + 200 * 4;               // 200*49*32 = 313600 floats
    float* ws_small = ws_part + 200 * NCHUNK * 32;      // 313600 floats
    /* crop scratch (20 MB) lives in out's big_img region; uncrop overwrites it last */
    float* ws_crop  = out + O_BIG_IMG;

    hipLaunchKernelGGL(topk_misc_kernel, dim3(B), dim3(64), 0, stream,
                       logit_mu, zwhere_mu, zwhere_std, w_zwhere, b_zwhere, out, ws_boxes);
    hipLaunchKernelGGL(crop_writer_kernel, dim3(49, 200), dim3(128), 0, stream,
                       features, ws_boxes, ws_crop);
    hipLaunchKernelGGL(enc_gemm_kernel, dim3(25 * NCHUNK), dim3(512), 0, stream,
                       ws_crop, w_enc_mu, w_enc_std, ws_part);
    hipLaunchKernelGGL(dec_enc_kernel, dim3(K * B), dim3(256), 0, stream,
                       ws_part, b_enc_mu, b_enc_std, w_dec, b_dec, ws_small, out);
    hipLaunchKernelGGL(uncrop_kernel, dim3(B * 64), dim3(256), 0, stream,
                       ws_small, ws_boxes, out);
}

// Round 6
// 128.799 us; speedup vs baseline: 1.1675x; 1.0410x over previous
//
#include <hip/hip_runtime.h>
#include <math.h>

#define B 8
#define FCH 32
#define WI 256
#define HI 256
#define NW 32
#define NH 32
#define NBOX 1024
#define K 25
#define S 28
#define DZI 16
#define FEAT_FLAT (FCH*S*S)   /* 25088 */
#define FEAT4 (FEAT_FLAT/4)   /* 6272 */
#define OUT_FLAT (2*S*S)      /* 1568 */
#define SMIN 24.0f
#define SMAX 96.0f
#define BIG_SZ (K*B*WI*HI)    /* 13,107,200 */

#define NCHUNK 49
#define CH4 128               /* float4 groups per chunk */

/* output offsets (floats), in reference return order */
#define O_LOGIT_MU    0
#define O_LOGIT_FEW   8192
#define O_BIG_MASK    8392
#define O_BIG_MASK_NON (O_BIG_MASK + BIG_SZ)
#define O_BIG_IMG     (O_BIG_MASK_NON + BIG_SZ)
#define O_P_MAP       (O_BIG_IMG + BIG_SZ)
#define O_C_FEW       (O_P_MAP + 8192)
#define O_BX          (O_C_FEW + 200)
#define O_BY          (O_BX + 200)
#define O_BW          (O_BY + 200)
#define O_BH          (O_BW + 200)
#define O_Z_SAMPLE    (O_BH + 200)
#define O_KL_LOGIT    (O_Z_SAMPLE + 3200)
#define O_KL_ZWHERE   (O_KL_LOGIT + 8192)
#define O_KL_ZINST    (O_KL_ZWHERE + 800)

__device__ __forceinline__ float sigmoidf_(float x) { return 1.0f / (1.0f + expf(-x)); }
__device__ __forceinline__ float softplusf_(float x) { return fmaxf(x, 0.0f) + log1pf(expf(-fabsf(x))); }
__device__ __forceinline__ float sig_fast(float x) { return 1.0f / (1.0f + __expf(-x)); }
__device__ __forceinline__ float sp_fast(float x)  { return fmaxf(x, 0.0f) + __logf(1.0f + __expf(-fabsf(x))); }
__device__ __forceinline__ float tanh_fast(float x) { /* x >= 0 */
    float e = __expf(-2.0f * x);
    return (1.0f - e) / (1.0f + e);
}

__device__ __forceinline__ float tap256(const float* img, int x, int y) {
    bool in = ((unsigned)x < 256u) && ((unsigned)y < 256u);
    int xc = min(max(x, 0), 255), yc = min(max(y, 0), 255);
    float v = img[xc * 256 + yc];
    return in ? v : 0.0f;
}

__device__ __forceinline__ float tap28(const float* img, int x, int y) {
    bool in = ((unsigned)x < 28u) && ((unsigned)y < 28u);
    int xc = min(max(x, 0), 27), yc = min(max(y, 0), 27);
    float v = img[xc * 28 + yc];
    return in ? v : 0.0f;
}

/* ------------- kernel T: misc maps + per-batch top-k + box params + kl_zwhere ------------- */
__global__ void topk_misc_kernel(const float* __restrict__ logit_mu,
                                 const float* __restrict__ zmu, const float* __restrict__ zstd,
                                 const float* __restrict__ w_zw, const float* __restrict__ b_zw,
                                 float* __restrict__ out, float* __restrict__ ws_boxes) {
    int b = blockIdx.x;
    int lane = threadIdx.x;          // 64 lanes, one wave
    const float* lg = logit_mu + b * NBOX;
    float vals[16];
    #pragma unroll
    for (int m = 0; m < 16; ++m) vals[m] = lg[m * 64 + lane];

    #pragma unroll
    for (int m = 0; m < 16; ++m) {
        int idx = b * NBOX + m * 64 + lane;
        float x = vals[m];
        out[O_LOGIT_MU + idx] = x;
        float p = sigmoidf_(x);
        out[O_P_MAP + idx] = p;
        out[O_KL_LOGIT + idx] = 0.69314718055994531f + p * logf(p + 1e-8f) + (1.0f - p) * logf(1.0f - p + 1e-8f);
    }

    unsigned taken = 0;
    int sel_idx = 0;
    for (int ks = 0; ks < K; ++ks) {
        float bv = -INFINITY; int bi = 0x7fffffff;
        #pragma unroll
        for (int m = 0; m < 16; ++m) {
            if (!(taken & (1u << m))) {
                float v = vals[m]; int idx = m * 64 + lane;
                if (v > bv || (v == bv && idx < bi)) { bv = v; bi = idx; }
            }
        }
        #pragma unroll
        for (int sh = 32; sh >= 1; sh >>= 1) {
            float ov = __shfl_xor(bv, sh);
            int   oi = __shfl_xor(bi, sh);
            if (ov > bv || (ov == bv && oi < bi)) { bv = ov; bi = oi; }
        }
        if ((bi & 63) == lane) taken |= (1u << (bi >> 6));
        if (lane == ks) sel_idx = bi;
        if (lane == 0) {
            out[O_LOGIT_FEW + ks * B + b] = bv;
            out[O_C_FEW + ks * B + b] = sigmoidf_(bv);
        }
    }

    if (lane < K) {
        int idx = sel_idx;
        int w = idx >> 5, h = idx & 31;
        float mu_c[4];
        #pragma unroll
        for (int c = 0; c < 4; ++c) mu_c[c] = zmu[((b * 4 + c) * NW + w) * NH + h];
        float t[4];
        #pragma unroll
        for (int o = 0; o < 4; ++o) {
            float a = b_zw[o];
            #pragma unroll
            for (int c = 0; c < 4; ++c) a = fmaf(mu_c[c], w_zw[o * 4 + c], a);
            t[o] = sigmoidf_(a);
        }
        float bx = (float)WI * ((float)w + t[0]) / (float)NW;
        float by = (float)HI * ((float)h + t[1]) / (float)NH;
        float bw = SMIN + (SMAX - SMIN) * t[2];
        float bh = SMIN + (SMAX - SMIN) * t[3];
        int kb = lane * B + b;
        out[O_BX + kb] = bx;
        out[O_BY + kb] = by;
        out[O_BW + kb] = bw;
        out[O_BH + kb] = bh;
        ((float4*)ws_boxes)[kb] = make_float4(bx, by, bw, bh);
        #pragma unroll
        for (int c = 0; c < 4; ++c) {
            float m = mu_c[c];
            float sd = zstd[((b * 4 + c) * NW + w) * NH + h];
            out[O_KL_ZWHERE + kb * 4 + c] = 0.5f * (sd * sd + m * m - 1.0f) - logf(sd);
        }
    }
}

/* ------------- kernel W: materialize crops (pure gather, massive TLP) ------------- */
__device__ __forceinline__ void csample4(const float* __restrict__ fb, int i4,
                                         float x_lo, float y_lo, float swx, float swy,
                                         float v[4]) {
    int i = i4 << 2;
    unsigned c = (unsigned)i / 784u;
    unsigned s = (unsigned)i - c * 784u;
    unsigned ix = s / 28u;
    unsigned iy = s - ix * 28u;          /* iy multiple of 4; group stays in one row */
    const float* img = fb + (size_t)c * (WI * HI);
    float px = fmaf((float)ix, swx, x_lo);
    float x0f = floorf(px); float fx = px - x0f; int x0 = (int)x0f;
    #pragma unroll
    for (int q = 0; q < 4; ++q) {
        float py = fmaf((float)(iy + q), swy, y_lo);
        float y0f = floorf(py); float fy = py - y0f; int y0 = (int)y0f;
        float a00 = tap256(img, x0, y0),     a01 = tap256(img, x0, y0 + 1);
        float a10 = tap256(img, x0 + 1, y0), a11 = tap256(img, x0 + 1, y0 + 1);
        v[q] = (1.0f - fx) * ((1.0f - fy) * a00 + fy * a01)
             +         fx  * ((1.0f - fy) * a10 + fy * a11);
    }
}

__global__ __launch_bounds__(128) void crop_writer_kernel(
        const float* __restrict__ features, const float* __restrict__ ws_boxes,
        float* __restrict__ crop) {
    int kb = blockIdx.y;
    int i4 = blockIdx.x * 128 + threadIdx.x;
    int b = kb & 7;
    float4 box = ((const float4*)ws_boxes)[kb];
    float x_lo = box.x - 0.5f * box.z, y_lo = box.y - 0.5f * box.w;
    float swx = box.z * (1.0f / 27.0f), swy = box.w * (1.0f / 27.0f);
    const float* fb = features + (size_t)b * (FCH * WI * HI);
    float v[4];
    csample4(fb, i4, x_lo, y_lo, swx, swy, v);
    ((float4*)crop)[(size_t)kb * FEAT4 + i4] = make_float4(v[0], v[1], v[2], v[3]);
}

/* ------------- kernel G: box-shared split-K encoder GEMM -------------
   grid = 25 box-groups x 49 chunks; block 512 (8 waves).
   Block: 8 boxes' crop chunk staged in LDS (16 KB); wave w owns 4 output rows
   (w*4..w*4+3 of 32 = 16 mu + 16 std); per lane: 8 staged weight float4,
   32 accs (4 rows x 8 boxes). Weights read ONCE per block. */
__device__ __forceinline__ float dot4f(float4 v, float4 w, float a) {
    return fmaf(v.x, w.x, fmaf(v.y, w.y, fmaf(v.z, w.z, fmaf(v.w, w.w, a))));
}

__global__ __launch_bounds__(512) void enc_gemm_kernel(
        const float* __restrict__ crop,
        const float* __restrict__ w_mu, const float* __restrict__ w_std,
        float* __restrict__ ws_part) {
    int blk = blockIdx.x;
    int g = blk / NCHUNK, chunk = blk - g * NCHUNK;
    int wave = threadIdx.x >> 6, lane = threadIdx.x & 63;
    int base4 = chunk * CH4;
    const float4* cp4 = (const float4*)crop;

    __shared__ float4 crop_lds[8][CH4];   /* 16 KB */
    {
        int t1 = threadIdx.x, t2 = threadIdx.x + 512;
        crop_lds[t1 >> 7][t1 & 127] = cp4[(size_t)(g * 8 + (t1 >> 7)) * FEAT4 + base4 + (t1 & 127)];
        crop_lds[t2 >> 7][t2 & 127] = cp4[(size_t)(g * 8 + (t2 >> 7)) * FEAT4 + base4 + (t2 & 127)];
    }

    /* stage this wave's 4 weight rows (rows w*4.. of 32; 0-15 mu, 16-31 std) */
    int row = wave * 4;
    const float4* wsrc = (row < 16) ? ((const float4*)w_mu + (size_t)row * FEAT4)
                                    : ((const float4*)w_std + (size_t)(row - 16) * FEAT4);
    int i4a = base4 + lane, i4b = i4a + 64;
    float4 wa[4], wb[4];
    #pragma unroll
    for (int r = 0; r < 4; ++r) {
        wa[r] = wsrc[(size_t)r * FEAT4 + i4a];
        wb[r] = wsrc[(size_t)r * FEAT4 + i4b];
    }

    float cur[32];
    #pragma unroll
    for (int j = 0; j < 32; ++j) cur[j] = 0.0f;

    __syncthreads();

    #pragma unroll
    for (int bb = 0; bb < 8; ++bb) {
        float4 ca = crop_lds[bb][lane];
        float4 cb = crop_lds[bb][lane + 64];
        #pragma unroll
        for (int r = 0; r < 4; ++r)
            cur[r * 8 + bb] = dot4f(cb, wb[r], dot4f(ca, wa[r], cur[r * 8 + bb]));
    }

    /* pairing-tree reduce: lane l<32 ends holding full 64-lane sum of cur[l] */
    {   bool bit = (lane & 1) != 0; float nx[16];
        #pragma unroll
        for (int j = 0; j < 16; ++j) {
            float keep = bit ? cur[2*j+1] : cur[2*j];
            float send = bit ? cur[2*j]   : cur[2*j+1];
            nx[j] = keep + __shfl_xor(send, 1);
        }
        #pragma unroll
        for (int j = 0; j < 16; ++j) cur[j] = nx[j];
    }
    {   bool bit = (lane & 2) != 0; float nx[8];
        #pragma unroll
        for (int j = 0; j < 8; ++j) {
            float keep = bit ? cur[2*j+1] : cur[2*j];
            float send = bit ? cur[2*j]   : cur[2*j+1];
            nx[j] = keep + __shfl_xor(send, 2);
        }
        #pragma unroll
        for (int j = 0; j < 8; ++j) cur[j] = nx[j];
    }
    {   bool bit = (lane & 4) != 0; float nx[4];
        #pragma unroll
        for (int j = 0; j < 4; ++j) {
            float keep = bit ? cur[2*j+1] : cur[2*j];
            float send = bit ? cur[2*j]   : cur[2*j+1];
            nx[j] = keep + __shfl_xor(send, 4);
        }
        #pragma unroll
        for (int j = 0; j < 4; ++j) cur[j] = nx[j];
    }
    {   bool bit = (lane & 8) != 0; float nx[2];
        #pragma unroll
        for (int j = 0; j < 2; ++j) {
            float keep = bit ? cur[2*j+1] : cur[2*j];
            float send = bit ? cur[2*j]   : cur[2*j+1];
            nx[j] = keep + __shfl_xor(send, 8);
        }
        cur[0] = nx[0]; cur[1] = nx[1];
    }
    {   bool bit = (lane & 16) != 0;
        float keep = bit ? cur[1] : cur[0];
        float send = bit ? cur[0] : cur[1];
        cur[0] = keep + __shfl_xor(send, 16);
    }
    float tot = cur[0] + __shfl_xor(cur[0], 32);
    if (lane < 32) {
        /* cur index j = r*8 + bb  ->  row = wave*4 + (j>>3), box = g*8 + (j&7) */
        int kbx = g * 8 + (lane & 7);
        ws_part[((size_t)kbx * NCHUNK + chunk) * 32 + row + (lane >> 3)] = tot;
    }
}

/* ------------- kernel D: finish encoder + decoder GEMV + activations ------------- */
__global__ __launch_bounds__(256) void dec_enc_kernel(
        const float* __restrict__ ws_part,
        const float* __restrict__ b_mu, const float* __restrict__ b_std,
        const float* __restrict__ w_dec, const float* __restrict__ b_dec,
        float* __restrict__ ws_small, float* __restrict__ out) {
    int kb = blockIdx.x;
    int t = threadIdx.x;
    __shared__ float zsh[DZI], spsh[DZI];
    if (t < 32) {
        float s = 0.0f;
        for (int c = 0; c < NCHUNK; ++c) s += ws_part[((size_t)kb * NCHUNK + c) * 32 + t];
        if (t < DZI) zsh[t] = s + b_mu[t];
        else         spsh[t - DZI] = s + b_std[t - DZI];
    }
    __syncthreads();
    if (t < DZI) {
        float m = zsh[t];
        float sd = softplusf_(spsh[t]);
        out[O_Z_SAMPLE + kb * DZI + t] = m;
        out[O_KL_ZINST + kb * DZI + t] = 0.5f * (sd * sd + m * m - 1.0f) - logf(sd + 1e-8f);
    }
    float z[DZI];
    #pragma unroll
    for (int j = 0; j < DZI; ++j) z[j] = zsh[j];
    for (int o = t; o < OUT_FLAT; o += 256) {
        const float4* wd = (const float4*)(w_dec + o * DZI);
        float4 w0 = wd[0], w1 = wd[1], w2 = wd[2], w3 = wd[3];
        float a = b_dec[o];
        a = fmaf(z[0], w0.x, fmaf(z[1], w0.y, fmaf(z[2], w0.z, fmaf(z[3], w0.w, a))));
        a = fmaf(z[4], w1.x, fmaf(z[5], w1.y, fmaf(z[6], w1.z, fmaf(z[7], w1.w, a))));
        a = fmaf(z[8], w2.x, fmaf(z[9], w2.y, fmaf(z[10], w2.z, fmaf(z[11], w2.w, a))));
        a = fmaf(z[12], w3.x, fmaf(z[13], w3.y, fmaf(z[14], w3.z, fmaf(z[15], w3.w, a))));
        float r = (o < 784) ? sp_fast(a) : sig_fast(a);
        ws_small[(size_t)kb * OUT_FLAT + o] = r;
    }
}

/* ------------- kernel E: uncrop + mask compose, float4 stores ------------- */
__device__ __forceinline__ void sample4_wi(const float* __restrict__ p0, float sx,
                                           float y_lo, float ih, int v0,
                                           float* __restrict__ w, float* __restrict__ im) {
    const float* p1 = p0 + 784;
    float x0f = floorf(sx); float fx = sx - x0f; int x0 = (int)x0f;
    #pragma unroll
    for (int q = 0; q < 4; ++q) {
        float sy = ((float)(v0 + q) - y_lo) * ih;
        float wv = 0.0f, iv = 0.0f;
        if (sy > -1.0f && sy < 28.0f) {
            float y0f = floorf(sy); float fy = sy - y0f; int y0 = (int)y0f;
            float a00 = tap28(p0, x0, y0),     a01 = tap28(p0, x0, y0 + 1);
            float a10 = tap28(p0, x0 + 1, y0), a11 = tap28(p0, x0 + 1, y0 + 1);
            wv = (1.0f - fx) * ((1.0f - fy) * a00 + fy * a01)
               +         fx  * ((1.0f - fy) * a10 + fy * a11);
            float c00 = tap28(p1, x0, y0),     c01 = tap28(p1, x0, y0 + 1);
            float c10 = tap28(p1, x0 + 1, y0), c11 = tap28(p1, x0 + 1, y0 + 1);
            iv = (1.0f - fx) * ((1.0f - fy) * c00 + fy * c01)
               +         fx  * ((1.0f - fy) * c10 + fy * c11);
        }
        w[q] = wv; im[q] = iv;
    }
}

__device__ __forceinline__ void sample4_w(const float* __restrict__ p0, float sx,
                                          float y_lo, float ih, int v0,
                                          float* __restrict__ w) {
    float x0f = floorf(sx); float fx = sx - x0f; int x0 = (int)x0f;
    #pragma unroll
    for (int q = 0; q < 4; ++q) {
        float sy = ((float)(v0 + q) - y_lo) * ih;
        float wv = 0.0f;
        if (sy > -1.0f && sy < 28.0f) {
            float y0f = floorf(sy); float fy = sy - y0f; int y0 = (int)y0f;
            float a00 = tap28(p0, x0, y0),     a01 = tap28(p0, x0, y0 + 1);
            float a10 = tap28(p0, x0 + 1, y0), a11 = tap28(p0, x0 + 1, y0 + 1);
            wv = (1.0f - fx) * ((1.0f - fy) * a00 + fy * a01)
               +         fx  * ((1.0f - fy) * a10 + fy * a11);
        }
        w[q] = wv;
    }
}

__global__ __launch_bounds__(256) void uncrop_kernel(const float* __restrict__ ws_small,
                                                     const float* __restrict__ ws_boxes,
                                                     float* __restrict__ out) {
    int blk = blockIdx.x;
    int b = blk >> 6;
    int u0 = (blk & 63) << 2;
    int t = threadIdx.x;
    int u = u0 + (t >> 6);
    int v0 = (t & 63) << 2;

    __shared__ float4 bt[K];   // (x_lo, y_lo, 27/cw, 27/ch)
    if (t < K) {
        float4 bx = ((const float4*)ws_boxes)[t * B + b];
        bt[t] = make_float4(bx.x - 0.5f * bx.z, bx.y - 0.5f * bx.w, 27.0f / bx.z, 27.0f / bx.w);
    }
    __syncthreads();

    float fu = (float)u;
    float sum[4] = {0.0f, 0.0f, 0.0f, 0.0f};
    #pragma unroll 2
    for (int k = 0; k < K; ++k) {
        float4 bb = bt[k];
        float sx = (fu - bb.x) * bb.z;
        float w[4] = {0, 0, 0, 0}, im[4] = {0, 0, 0, 0};
        if (sx > -1.0f && sx < 28.0f) {
            const float* p0 = ws_small + (size_t)(k * B + b) * OUT_FLAT;
            sample4_wi(p0, sx, bb.y, bb.w, v0, w, im);
        }
        #pragma unroll
        for (int q = 0; q < 4; ++q) sum[q] += w[q];
        size_t base = (((size_t)(k * B + b) * 256 + u) * 256 + v0);
        *(float4*)(out + O_BIG_IMG + base) = make_float4(im[0], im[1], im[2], im[3]);
        *(float4*)(out + O_BIG_MASK_NON + base) =
            make_float4(tanh_fast(w[0]), tanh_fast(w[1]), tanh_fast(w[2]), tanh_fast(w[3]));
    }
    float sc[4];
    #pragma unroll
    for (int q = 0; q < 4; ++q) sc[q] = tanh_fast(sum[q]) / fmaxf(sum[q], 1e-6f);
    #pragma unroll 2
    for (int k = 0; k < K; ++k) {
        float4 bb = bt[k];
        float sx = (fu - bb.x) * bb.z;
        float w[4] = {0, 0, 0, 0};
        if (sx > -1.0f && sx < 28.0f) {
            const float* p0 = ws_small + (size_t)(k * B + b) * OUT_FLAT;
            sample4_w(p0, sx, bb.y, bb.w, v0, w);
        }
        size_t base = (((size_t)(k * B + b) * 256 + u) * 256 + v0);
        *(float4*)(out + O_BIG_MASK + base) =
            make_float4(w[0] * sc[0], w[1] * sc[1], w[2] * sc[2], w[3] * sc[3]);
    }
}

extern "C" void kernel_launch(void* const* d_in, const int* in_sizes, int n_in,
                              void* d_out, int out_size, void* d_ws, size_t ws_size,
                              hipStream_t stream) {
    const float* features = (const float*)d_in[1];
    const float* zwhere_mu = (const float*)d_in[2];
    const float* zwhere_std = (const float*)d_in[3];
    const float* logit_mu = (const float*)d_in[4];
    const float* w_zwhere = (const float*)d_in[5];
    const float* b_zwhere = (const float*)d_in[6];
    const float* w_enc_mu = (const float*)d_in[7];
    const float* b_enc_mu = (const float*)d_in[8];
    const float* w_enc_std = (const float*)d_in[9];
    const float* b_enc_std = (const float*)d_in[10];
    const float* w_dec = (const float*)d_in[11];
    const float* b_dec = (const float*)d_in[12];
    float* out = (float*)d_out;

    float* ws_boxes = (float*)d_ws;                     // 800 floats
    float* ws_part  = ws_boxes + 200 * 4;               // 200*49*32 = 313600 floats
    float* ws_small = ws_part + 200 * NCHUNK * 32;      // 313600 floats
    /* crop scratch (20 MB) lives in out's big_img region; uncrop overwrites it last */
    float* ws_crop  = out + O_BIG_IMG;

    hipLaunchKernelGGL(topk_misc_kernel, dim3(B), dim3(64), 0, stream,
                       logit_mu, zwhere_mu, zwhere_std, w_zwhere, b_zwhere, out, ws_boxes);
    hipLaunchKernelGGL(crop_writer_kernel, dim3(49, 200), dim3(128), 0, stream,
                       features, ws_boxes, ws_crop);
    hipLaunchKernelGGL(enc_gemm_kernel, dim3(25 * NCHUNK), dim3(512), 0, stream,
                       ws_crop, w_enc_mu, w_enc_std, ws_part);
    hipLaunchKernelGGL(dec_enc_kernel, dim3(K * B), dim3(256), 0, stream,
                       ws_part, b_enc_mu, b_enc_std, w_dec, b_dec, ws_small, out);
    hipLaunchKernelGGL(uncrop_kernel, dim3(B * 64), dim3(256), 0, stream,
                       ws_small, ws_boxes, out);
}

// Round 7
// 125.666 us; speedup vs baseline: 1.1967x; 1.0249x over previous
//
#include <hip/hip_runtime.h>
#include <math.h>

#define B 8
#define FCH 32
#define WI 256
#define HI 256
#define NW 32
#define NH 32
#define NBOX 1024
#define K 25
#define S 28
#define DZI 16
#define FEAT_FLAT (FCH*S*S)   /* 25088 */
#define FEAT4 (FEAT_FLAT/4)   /* 6272 */
#define OUT_FLAT (2*S*S)      /* 1568 */
#define SMIN 24.0f
#define SMAX 96.0f
#define BIG_SZ (K*B*WI*HI)    /* 13,107,200 */

#define NCHUNK 49
#define CH4 128               /* float4 groups per chunk */

/* output offsets (floats), in reference return order */
#define O_LOGIT_MU    0
#define O_LOGIT_FEW   8192
#define O_BIG_MASK    8392
#define O_BIG_MASK_NON (O_BIG_MASK + BIG_SZ)
#define O_BIG_IMG     (O_BIG_MASK_NON + BIG_SZ)
#define O_P_MAP       (O_BIG_IMG + BIG_SZ)
#define O_C_FEW       (O_P_MAP + 8192)
#define O_BX          (O_C_FEW + 200)
#define O_BY          (O_BX + 200)
#define O_BW          (O_BY + 200)
#define O_BH          (O_BW + 200)
#define O_Z_SAMPLE    (O_BH + 200)
#define O_KL_LOGIT    (O_Z_SAMPLE + 3200)
#define O_KL_ZWHERE   (O_KL_LOGIT + 8192)
#define O_KL_ZINST    (O_KL_ZWHERE + 800)

__device__ __forceinline__ float sigmoidf_(float x) { return 1.0f / (1.0f + expf(-x)); }
__device__ __forceinline__ float softplusf_(float x) { return fmaxf(x, 0.0f) + log1pf(expf(-fabsf(x))); }
__device__ __forceinline__ float sig_fast(float x) { return 1.0f / (1.0f + __expf(-x)); }
__device__ __forceinline__ float sp_fast(float x)  { return fmaxf(x, 0.0f) + __logf(1.0f + __expf(-fabsf(x))); }
__device__ __forceinline__ float tanh_fast(float x) { /* x >= 0 */
    float e = __expf(-2.0f * x);
    return (1.0f - e) / (1.0f + e);
}

__device__ __forceinline__ float tap256(const float* img, int x, int y) {
    bool in = ((unsigned)x < 256u) && ((unsigned)y < 256u);
    int xc = min(max(x, 0), 255), yc = min(max(y, 0), 255);
    float v = img[xc * 256 + yc];
    return in ? v : 0.0f;
}

__device__ __forceinline__ float tap28(const float* img, int x, int y) {
    bool in = ((unsigned)x < 28u) && ((unsigned)y < 28u);
    int xc = min(max(x, 0), 27), yc = min(max(y, 0), 27);
    float v = img[xc * 28 + yc];
    return in ? v : 0.0f;
}

/* ------------- kernel T: misc maps + per-batch top-k + box params + kl_zwhere ------------- */
__global__ void topk_misc_kernel(const float* __restrict__ logit_mu,
                                 const float* __restrict__ zmu, const float* __restrict__ zstd,
                                 const float* __restrict__ w_zw, const float* __restrict__ b_zw,
                                 float* __restrict__ out, float* __restrict__ ws_boxes) {
    int b = blockIdx.x;
    int lane = threadIdx.x;          // 64 lanes, one wave
    const float* lg = logit_mu + b * NBOX;
    float vals[16];
    #pragma unroll
    for (int m = 0; m < 16; ++m) vals[m] = lg[m * 64 + lane];

    #pragma unroll
    for (int m = 0; m < 16; ++m) {
        int idx = b * NBOX + m * 64 + lane;
        float x = vals[m];
        out[O_LOGIT_MU + idx] = x;
        float p = sigmoidf_(x);
        out[O_P_MAP + idx] = p;
        out[O_KL_LOGIT + idx] = 0.69314718055994531f + p * logf(p + 1e-8f) + (1.0f - p) * logf(1.0f - p + 1e-8f);
    }

    unsigned taken = 0;
    int sel_idx = 0;
    for (int ks = 0; ks < K; ++ks) {
        float bv = -INFINITY; int bi = 0x7fffffff;
        #pragma unroll
        for (int m = 0; m < 16; ++m) {
            if (!(taken & (1u << m))) {
                float v = vals[m]; int idx = m * 64 + lane;
                if (v > bv || (v == bv && idx < bi)) { bv = v; bi = idx; }
            }
        }
        #pragma unroll
        for (int sh = 32; sh >= 1; sh >>= 1) {
            float ov = __shfl_xor(bv, sh);
            int   oi = __shfl_xor(bi, sh);
            if (ov > bv || (ov == bv && oi < bi)) { bv = ov; bi = oi; }
        }
        if ((bi & 63) == lane) taken |= (1u << (bi >> 6));
        if (lane == ks) sel_idx = bi;
        if (lane == 0) {
            out[O_LOGIT_FEW + ks * B + b] = bv;
            out[O_C_FEW + ks * B + b] = sigmoidf_(bv);
        }
    }

    if (lane < K) {
        int idx = sel_idx;
        int w = idx >> 5, h = idx & 31;
        float mu_c[4];
        #pragma unroll
        for (int c = 0; c < 4; ++c) mu_c[c] = zmu[((b * 4 + c) * NW + w) * NH + h];
        float t[4];
        #pragma unroll
        for (int o = 0; o < 4; ++o) {
            float a = b_zw[o];
            #pragma unroll
            for (int c = 0; c < 4; ++c) a = fmaf(mu_c[c], w_zw[o * 4 + c], a);
            t[o] = sigmoidf_(a);
        }
        float bx = (float)WI * ((float)w + t[0]) / (float)NW;
        float by = (float)HI * ((float)h + t[1]) / (float)NH;
        float bw = SMIN + (SMAX - SMIN) * t[2];
        float bh = SMIN + (SMAX - SMIN) * t[3];
        int kb = lane * B + b;
        out[O_BX + kb] = bx;
        out[O_BY + kb] = by;
        out[O_BW + kb] = bw;
        out[O_BH + kb] = bh;
        ((float4*)ws_boxes)[kb] = make_float4(bx, by, bw, bh);
        #pragma unroll
        for (int c = 0; c < 4; ++c) {
            float m = mu_c[c];
            float sd = zstd[((b * 4 + c) * NW + w) * NH + h];
            out[O_KL_ZWHERE + kb * 4 + c] = 0.5f * (sd * sd + m * m - 1.0f) - logf(sd);
        }
    }
}

/* ------------- fused kernel G: gather crops into LDS + box-shared split-K GEMM -------------
   grid = 25 box-groups x 49 chunks; block 512 (8 waves).
   Phase 1: each thread gathers 2 float4 crop groups (box is wave-uniform) -> LDS (16 KB).
   Phase 2: wave w owns 4 output rows of 32 (16 mu + 16 std); 8 staged weight float4
   per lane (loads issued before the sync, hiding under the gather); 32 accs. */
__device__ __forceinline__ float dot4f(float4 v, float4 w, float a) {
    return fmaf(v.x, w.x, fmaf(v.y, w.y, fmaf(v.z, w.z, fmaf(v.w, w.w, a))));
}

__device__ __forceinline__ void csample4(const float* __restrict__ fb, int i4,
                                         float x_lo, float y_lo, float swx, float swy,
                                         float v[4]) {
    int i = i4 << 2;
    unsigned c = (unsigned)i / 784u;
    unsigned s = (unsigned)i - c * 784u;
    unsigned ix = s / 28u;
    unsigned iy = s - ix * 28u;          /* iy multiple of 4; group stays in one row */
    const float* img = fb + (size_t)c * (WI * HI);
    float px = fmaf((float)ix, swx, x_lo);
    float x0f = floorf(px); float fx = px - x0f; int x0 = (int)x0f;
    #pragma unroll
    for (int q = 0; q < 4; ++q) {
        float py = fmaf((float)(iy + q), swy, y_lo);
        float y0f = floorf(py); float fy = py - y0f; int y0 = (int)y0f;
        float a00 = tap256(img, x0, y0),     a01 = tap256(img, x0, y0 + 1);
        float a10 = tap256(img, x0 + 1, y0), a11 = tap256(img, x0 + 1, y0 + 1);
        v[q] = (1.0f - fx) * ((1.0f - fy) * a00 + fy * a01)
             +         fx  * ((1.0f - fy) * a10 + fy * a11);
    }
}

__global__ __launch_bounds__(512) void crop_gemm_kernel(
        const float* __restrict__ features,
        const float* __restrict__ w_mu, const float* __restrict__ w_std,
        const float* __restrict__ ws_boxes, float* __restrict__ ws_part) {
    int blk = blockIdx.x;
    int g = blk / NCHUNK, chunk = blk - g * NCHUNK;
    int wave = threadIdx.x >> 6, lane = threadIdx.x & 63;
    int base4 = chunk * CH4;

    __shared__ float4 crop_lds[8][CH4];   /* 16 KB */

    /* stage this wave's 4 weight rows first (in flight during the gather) */
    int row = wave * 4;
    const float4* wsrc = (row < 16) ? ((const float4*)w_mu + (size_t)row * FEAT4)
                                    : ((const float4*)w_std + (size_t)(row - 16) * FEAT4);
    int i4a = base4 + lane, i4b = i4a + 64;
    float4 wa[4], wb[4];
    #pragma unroll
    for (int r = 0; r < 4; ++r) {
        wa[r] = wsrc[(size_t)r * FEAT4 + i4a];
        wb[r] = wsrc[(size_t)r * FEAT4 + i4b];
    }

    /* gather: thread handles groups gidx = t and t+512; bb = gidx>>7 is wave-uniform */
    #pragma unroll
    for (int pass = 0; pass < 2; ++pass) {
        int gidx = threadIdx.x + pass * 512;
        int bb = gidx >> 7;
        int e  = gidx & 127;
        int kb = g * 8 + bb;
        float4 box = ((const float4*)ws_boxes)[kb];
        float x_lo = box.x - 0.5f * box.z, y_lo = box.y - 0.5f * box.w;
        float swx = box.z * (1.0f / 27.0f), swy = box.w * (1.0f / 27.0f);
        const float* fb = features + (size_t)(kb & 7) * (FCH * WI * HI);
        float v[4];
        csample4(fb, base4 + e, x_lo, y_lo, swx, swy, v);
        crop_lds[bb][e] = make_float4(v[0], v[1], v[2], v[3]);
    }

    float cur[32];
    #pragma unroll
    for (int j = 0; j < 32; ++j) cur[j] = 0.0f;

    __syncthreads();

    #pragma unroll
    for (int bb = 0; bb < 8; ++bb) {
        float4 ca = crop_lds[bb][lane];
        float4 cb = crop_lds[bb][lane + 64];
        #pragma unroll
        for (int r = 0; r < 4; ++r)
            cur[r * 8 + bb] = dot4f(cb, wb[r], dot4f(ca, wa[r], cur[r * 8 + bb]));
    }

    /* pairing-tree reduce: lane l<32 ends holding full 64-lane sum of cur[l] */
    {   bool bit = (lane & 1) != 0; float nx[16];
        #pragma unroll
        for (int j = 0; j < 16; ++j) {
            float keep = bit ? cur[2*j+1] : cur[2*j];
            float send = bit ? cur[2*j]   : cur[2*j+1];
            nx[j] = keep + __shfl_xor(send, 1);
        }
        #pragma unroll
        for (int j = 0; j < 16; ++j) cur[j] = nx[j];
    }
    {   bool bit = (lane & 2) != 0; float nx[8];
        #pragma unroll
        for (int j = 0; j < 8; ++j) {
            float keep = bit ? cur[2*j+1] : cur[2*j];
            float send = bit ? cur[2*j]   : cur[2*j+1];
            nx[j] = keep + __shfl_xor(send, 2);
        }
        #pragma unroll
        for (int j = 0; j < 8; ++j) cur[j] = nx[j];
    }
    {   bool bit = (lane & 4) != 0; float nx[4];
        #pragma unroll
        for (int j = 0; j < 4; ++j) {
            float keep = bit ? cur[2*j+1] : cur[2*j];
            float send = bit ? cur[2*j]   : cur[2*j+1];
            nx[j] = keep + __shfl_xor(send, 4);
        }
        #pragma unroll
        for (int j = 0; j < 4; ++j) cur[j] = nx[j];
    }
    {   bool bit = (lane & 8) != 0; float nx[2];
        #pragma unroll
        for (int j = 0; j < 2; ++j) {
            float keep = bit ? cur[2*j+1] : cur[2*j];
            float send = bit ? cur[2*j]   : cur[2*j+1];
            nx[j] = keep + __shfl_xor(send, 8);
        }
        cur[0] = nx[0]; cur[1] = nx[1];
    }
    {   bool bit = (lane & 16) != 0;
        float keep = bit ? cur[1] : cur[0];
        float send = bit ? cur[0] : cur[1];
        cur[0] = keep + __shfl_xor(send, 16);
    }
    float tot = cur[0] + __shfl_xor(cur[0], 32);
    if (lane < 32) {
        /* cur index j = r*8 + bb  ->  row = wave*4 + (j>>3), box = g*8 + (j&7) */
        int kbx = g * 8 + (lane & 7);
        ws_part[((size_t)kbx * NCHUNK + chunk) * 32 + row + (lane >> 3)] = tot;
    }
}

/* ------------- kernel D: finish encoder + decoder GEMV + activations ------------- */
__global__ __launch_bounds__(256) void dec_enc_kernel(
        const float* __restrict__ ws_part,
        const float* __restrict__ b_mu, const float* __restrict__ b_std,
        const float* __restrict__ w_dec, const float* __restrict__ b_dec,
        float* __restrict__ ws_small, float* __restrict__ out) {
    int kb = blockIdx.x;
    int t = threadIdx.x;
    __shared__ float zsh[DZI], spsh[DZI];
    if (t < 32) {
        float s = 0.0f;
        for (int c = 0; c < NCHUNK; ++c) s += ws_part[((size_t)kb * NCHUNK + c) * 32 + t];
        if (t < DZI) zsh[t] = s + b_mu[t];
        else         spsh[t - DZI] = s + b_std[t - DZI];
    }
    __syncthreads();
    if (t < DZI) {
        float m = zsh[t];
        float sd = softplusf_(spsh[t]);
        out[O_Z_SAMPLE + kb * DZI + t] = m;
        out[O_KL_ZINST + kb * DZI + t] = 0.5f * (sd * sd + m * m - 1.0f) - logf(sd + 1e-8f);
    }
    float z[DZI];
    #pragma unroll
    for (int j = 0; j < DZI; ++j) z[j] = zsh[j];
    for (int o = t; o < OUT_FLAT; o += 256) {
        const float4* wd = (const float4*)(w_dec + o * DZI);
        float4 w0 = wd[0], w1 = wd[1], w2 = wd[2], w3 = wd[3];
        float a = b_dec[o];
        a = fmaf(z[0], w0.x, fmaf(z[1], w0.y, fmaf(z[2], w0.z, fmaf(z[3], w0.w, a))));
        a = fmaf(z[4], w1.x, fmaf(z[5], w1.y, fmaf(z[6], w1.z, fmaf(z[7], w1.w, a))));
        a = fmaf(z[8], w2.x, fmaf(z[9], w2.y, fmaf(z[10], w2.z, fmaf(z[11], w2.w, a))));
        a = fmaf(z[12], w3.x, fmaf(z[13], w3.y, fmaf(z[14], w3.z, fmaf(z[15], w3.w, a))));
        float r = (o < 784) ? sp_fast(a) : sig_fast(a);
        ws_small[(size_t)kb * OUT_FLAT + o] = r;
    }
}

/* ------------- kernel E: uncrop + mask compose, float4 stores ------------- */
__device__ __forceinline__ void sample4_wi(const float* __restrict__ p0, float sx,
                                           float y_lo, float ih, int v0,
                                           float* __restrict__ w, float* __restrict__ im) {
    const float* p1 = p0 + 784;
    float x0f = floorf(sx); float fx = sx - x0f; int x0 = (int)x0f;
    #pragma unroll
    for (int q = 0; q < 4; ++q) {
        float sy = ((float)(v0 + q) - y_lo) * ih;
        float wv = 0.0f, iv = 0.0f;
        if (sy > -1.0f && sy < 28.0f) {
            float y0f = floorf(sy); float fy = sy - y0f; int y0 = (int)y0f;
            float a00 = tap28(p0, x0, y0),     a01 = tap28(p0, x0, y0 + 1);
            float a10 = tap28(p0, x0 + 1, y0), a11 = tap28(p0, x0 + 1, y0 + 1);
            wv = (1.0f - fx) * ((1.0f - fy) * a00 + fy * a01)
               +         fx  * ((1.0f - fy) * a10 + fy * a11);
            float c00 = tap28(p1, x0, y0),     c01 = tap28(p1, x0, y0 + 1);
            float c10 = tap28(p1, x0 + 1, y0), c11 = tap28(p1, x0 + 1, y0 + 1);
            iv = (1.0f - fx) * ((1.0f - fy) * c00 + fy * c01)
               +         fx  * ((1.0f - fy) * c10 + fy * c11);
        }
        w[q] = wv; im[q] = iv;
    }
}

__device__ __forceinline__ void sample4_w(const float* __restrict__ p0, float sx,
                                          float y_lo, float ih, int v0,
                                          float* __restrict__ w) {
    float x0f = floorf(sx); float fx = sx - x0f; int x0 = (int)x0f;
    #pragma unroll
    for (int q = 0; q < 4; ++q) {
        float sy = ((float)(v0 + q) - y_lo) * ih;
        float wv = 0.0f;
        if (sy > -1.0f && sy < 28.0f) {
            float y0f = floorf(sy); float fy = sy - y0f; int y0 = (int)y0f;
            float a00 = tap28(p0, x0, y0),     a01 = tap28(p0, x0, y0 + 1);
            float a10 = tap28(p0, x0 + 1, y0), a11 = tap28(p0, x0 + 1, y0 + 1);
            wv = (1.0f - fx) * ((1.0f - fy) * a00 + fy * a01)
               +         fx  * ((1.0f - fy) * a10 + fy * a11);
        }
        w[q] = wv;
    }
}

__global__ __launch_bounds__(256) void uncrop_kernel(const float* __restrict__ ws_small,
                                                     const float* __restrict__ ws_boxes,
                                                     float* __restrict__ out) {
    int blk = blockIdx.x;
    int b = blk >> 6;
    int u0 = (blk & 63) << 2;
    int t = threadIdx.x;
    int u = u0 + (t >> 6);
    int v0 = (t & 63) << 2;

    __shared__ float4 bt[K];   // (x_lo, y_lo, 27/cw, 27/ch)
    if (t < K) {
        float4 bx = ((const float4*)ws_boxes)[t * B + b];
        bt[t] = make_float4(bx.x - 0.5f * bx.z, bx.y - 0.5f * bx.w, 27.0f / bx.z, 27.0f / bx.w);
    }
    __syncthreads();

    float fu = (float)u;
    float sum[4] = {0.0f, 0.0f, 0.0f, 0.0f};
    #pragma unroll 2
    for (int k = 0; k < K; ++k) {
        float4 bb = bt[k];
        float sx = (fu - bb.x) * bb.z;
        float w[4] = {0, 0, 0, 0}, im[4] = {0, 0, 0, 0};
        if (sx > -1.0f && sx < 28.0f) {
            const float* p0 = ws_small + (size_t)(k * B + b) * OUT_FLAT;
            sample4_wi(p0, sx, bb.y, bb.w, v0, w, im);
        }
        #pragma unroll
        for (int q = 0; q < 4; ++q) sum[q] += w[q];
        size_t base = (((size_t)(k * B + b) * 256 + u) * 256 + v0);
        *(float4*)(out + O_BIG_IMG + base) = make_float4(im[0], im[1], im[2], im[3]);
        *(float4*)(out + O_BIG_MASK_NON + base) =
            make_float4(tanh_fast(w[0]), tanh_fast(w[1]), tanh_fast(w[2]), tanh_fast(w[3]));
    }
    float sc[4];
    #pragma unroll
    for (int q = 0; q < 4; ++q) sc[q] = tanh_fast(sum[q]) / fmaxf(sum[q], 1e-6f);
    #pragma unroll 2
    for (int k = 0; k < K; ++k) {
        float4 bb = bt[k];
        float sx = (fu - bb.x) * bb.z;
        float w[4] = {0, 0, 0, 0};
        if (sx > -1.0f && sx < 28.0f) {
            const float* p0 = ws_small + (size_t)(k * B + b) * OUT_FLAT;
            sample4_w(p0, sx, bb.y, bb.w, v0, w);
        }
        size_t base = (((size_t)(k * B + b) * 256 + u) * 256 + v0);
        *(float4*)(out + O_BIG_MASK + base) =
            make_float4(w[0] * sc[0], w[1] * sc[1], w[2] * sc[2], w[3] * sc[3]);
    }
}

extern "C" void kernel_launch(void* const* d_in, const int* in_sizes, int n_in,
                              void* d_out, int out_size, void* d_ws, size_t ws_size,
                              hipStream_t stream) {
    const float* features = (const float*)d_in[1];
    const float* zwhere_mu = (const float*)d_in[2];
    const float* zwhere_std = (const float*)d_in[3];
    const float* logit_mu = (const float*)d_in[4];
    const float* w_zwhere = (const float*)d_in[5];
    const float* b_zwhere = (const float*)d_in[6];
    const float* w_enc_mu = (const float*)d_in[7];
    const float* b_enc_mu = (const float*)d_in[8];
    const float* w_enc_std = (const float*)d_in[9];
    const float* b_enc_std = (const float*)d_in[10];
    const float* w_dec = (const float*)d_in[11];
    const float* b_dec = (const float*)d_in[12];
    float* out = (float*)d_out;

    float* ws_boxes = (float*)d_ws;                     // 800 floats
    float* ws_part  = ws_boxes + 200 * 4;               // 200*49*32 = 313600 floats
    float* ws_small = ws_part + 200 * NCHUNK * 32;      // 313600 floats

    hipLaunchKernelGGL(topk_misc_kernel, dim3(B), dim3(64), 0, stream,
                       logit_mu, zwhere_mu, zwhere_std, w_zwhere, b_zwhere, out, ws_boxes);
    hipLaunchKernelGGL(crop_gemm_kernel, dim3(25 * NCHUNK), dim3(512), 0, stream,
                       features, w_enc_mu, w_enc_std, ws_boxes, ws_part);
    hipLaunchKernelGGL(dec_enc_kernel, dim3(K * B), dim3(256), 0, stream,
                       ws_part, b_enc_mu, b_enc_std, w_dec, b_dec, ws_small, out);
    hipLaunchKernelGGL(uncrop_kernel, dim3(B * 64), dim3(256), 0, stream,
                       ws_small, ws_boxes, out);
}